// Round 17
// baseline (169.128 us; speedup 1.0000x reference)
//
#include <hip/hip_runtime.h>
#include <hip/hip_bf16.h>

// MultiHeadBatchedMixers, group-sorted two-kernel structure (no atomics):
//   prepack+sort: w1t,w2t,x,w1c,w2c -> bf16 ws (biases stay f32; L2-hot);
//                 block 0 builds order[768] (by (e,h)) / order2[384] (by (e0,h))
//   Kernel A (grid 1536x256, XCD-chunked, group-ordered): H = GELU(W1c @ X @ W1t^T + B1)
//       wave owns 64 e; MFMA1 ks-loop explicitly double-buffered (no barriers in loop)
//   Kernel B (grid 768x256, XCD-chunked, group-ordered): 4 waves = 2 k x 2 wq,
//       wave owns 64c x 64n; MFMA3 ks-loop double-buffered; LDS combine; f32 stores
// bf16 MFMA 16x16x32, f32 accumulate.
// NOTE (R8/R10): VGPR+AGPR share one file on gfx950; never min-waves-bound the
// MFMA kernels (reg cap -> accumulator spill -> WRITE blowup).
// NOTE (R12/R13/R14): cost tracks TOTAL load instructions & MFMA/load intensity;
// intensity-2 64x64 wave tiles beat high-occupancy thin tiles.
// NOTE (R15): e-half splitting a wave tile serializes phases; never split acc lifetimes.

namespace {
constexpr int NHEAD = 12, NTOK = 256, HDIM = 64, HIDD = 512, NBATCH = 32, TOPK = 2;
constexpr int NCHAIN = NBATCH * NHEAD * TOPK;  // 768
constexpr int NBH = NBATCH * NHEAD;            // 384
constexpr int NGROUP = 8 * NHEAD;              // 96

// Kernel A LDS: per-wave T1^T [64 e][64 d] bf16, pitch +16B
constexpr int P_T1 = HDIM * 2 + 16;   // 144
constexpr int T1_W = 64 * P_T1;       // 9216
constexpr int SMA_TOTAL = 4 * T1_W;   // 36864
// Kernel B LDS: per-wave T3^T [64 n][64 c] (4 waves); combine aliases [0,32768)
constexpr int P_T3 = HDIM * 2 + 16;   // 144
constexpr int T3_W = 64 * P_T3;       // 9216
constexpr int SMB_TOTAL = 4 * T3_W;   // 36864

// ws layout: [H][w1t][w2t][x][b1(unused)][b2(unused)][w1c][w2c] bf16, then orders
constexpr size_t SZ_H    = (size_t)NCHAIN * HDIM * HIDD;          // 25,165,824
constexpr size_t OFF_H   = 0;
constexpr size_t OFF_W1T = OFF_H + SZ_H;
constexpr size_t SZ_W1T  = (size_t)8 * NHEAD * HIDD * NTOK;       // 12,582,912
constexpr size_t OFF_W2T = OFF_W1T + SZ_W1T;
constexpr size_t SZ_W2T  = (size_t)8 * NHEAD * NTOK * HIDD;
constexpr size_t OFF_X   = OFF_W2T + SZ_W2T;
constexpr size_t SZ_X    = (size_t)NBATCH * NHEAD * HDIM * NTOK;  // 6,291,456
constexpr size_t OFF_B1  = OFF_X + SZ_X;
constexpr size_t SZ_B1   = (size_t)8 * NHEAD * HDIM * HIDD;
constexpr size_t OFF_B2  = OFF_B1 + SZ_B1;
constexpr size_t SZ_B2   = (size_t)8 * NHEAD * HDIM * NTOK;
constexpr size_t OFF_W1C = OFF_B2 + SZ_B2;
constexpr size_t SZ_W1C  = (size_t)8 * NHEAD * HDIM * HDIM;       // 393,216
constexpr size_t OFF_W2C = OFF_W1C + SZ_W1C;
constexpr size_t SZ_W2C  = (size_t)8 * NHEAD * HDIM * HDIM;
constexpr size_t TOTEL   = OFF_W2C + SZ_W2C;                      // shorts
constexpr size_t NEED    = TOTEL * 2 + (NCHAIN + NBH) * 4;
}

typedef float f32x4 __attribute__((ext_vector_type(4)));
typedef short bf16x8 __attribute__((ext_vector_type(8)));
typedef short bf16x4 __attribute__((ext_vector_type(4)));

#define MFMA16(a, b, c) __builtin_amdgcn_mfma_f32_16x16x32_bf16((a), (b), (c), 0, 0, 0)

__device__ __forceinline__ short f2bf(float f) {
  union { float f; unsigned u; } v; v.f = f;
  unsigned r = v.u + 0x7fffu + ((v.u >> 16) & 1u);
  return (short)(r >> 16);
}

__device__ __forceinline__ bf16x8 ld_gfrag(const float* p) {
  float4 a = *(const float4*)p;
  float4 b = *(const float4*)(p + 4);
  bf16x8 r;
  r[0] = f2bf(a.x); r[1] = f2bf(a.y); r[2] = f2bf(a.z); r[3] = f2bf(a.w);
  r[4] = f2bf(b.x); r[5] = f2bf(b.y); r[6] = f2bf(b.z); r[7] = f2bf(b.w);
  return r;
}

// gelu(x) = x * rcp(1 + exp2(-2.30220826 * x * (1 + 0.044715 x^2)))  [err ~1e-7 << bf16]
__device__ __forceinline__ float gelu_fast(float x) {
  float arg = -2.30220826f * x * __builtin_fmaf(0.044715f, x * x, 1.0f);
  float e = __builtin_amdgcn_exp2f(arg);
  return x * __builtin_amdgcn_rcpf(1.0f + e);
}

// XCD-chunk swizzle (nwg % 8 == 0): logical sequence contiguous per XCD.
__device__ __forceinline__ int xcd_chunk(int bx, int nwg) {
  return (bx & 7) * (nwg >> 3) + (bx >> 3);
}

// ---------------- Prepack (+ block-0 group sort); biases NOT converted ----------------
__global__ __launch_bounds__(256) void prepack_sort_kernel(
    const float* __restrict__ w1t, const float* __restrict__ w2t,
    const float* __restrict__ x, const float* __restrict__ w1c,
    const float* __restrict__ w2c, short* __restrict__ wsb,
    const int* __restrict__ eidx, int* __restrict__ order, int* __restrict__ order2) {
  if (blockIdx.x == 0) {
    __shared__ int keys[NCHAIN];
    __shared__ int keys2[NBH];
    __shared__ int cnt[NGROUP + 1];
    __shared__ int cnt2[NGROUP + 1];
    const int t = threadIdx.x;
    for (int i = t; i <= NGROUP; i += 256) { cnt[i] = 0; cnt2[i] = 0; }
    __syncthreads();
    for (int i = t; i < NCHAIN; i += 256) {
      int h = (i >> 1) % NHEAD;
      int key = eidx[i] * NHEAD + h;
      keys[i] = key;
      atomicAdd(&cnt[key + 1], 1);
    }
    for (int i = t; i < NBH; i += 256) {
      int h = i % NHEAD;
      int key = eidx[i * TOPK] * NHEAD + h;
      keys2[i] = key;
      atomicAdd(&cnt2[key + 1], 1);
    }
    __syncthreads();
    if (t == 0) for (int i = 1; i <= NGROUP; ++i) cnt[i] += cnt[i - 1];
    if (t == 1) for (int i = 1; i <= NGROUP; ++i) cnt2[i] += cnt2[i - 1];
    __syncthreads();
    for (int i = t; i < NCHAIN; i += 256) {
      int pos = atomicAdd(&cnt[keys[i]], 1);  // rank within group (order-agnostic downstream)
      order[pos] = i;
    }
    for (int i = t; i < NBH; i += 256) {
      int pos = atomicAdd(&cnt2[keys2[i]], 1);
      order2[pos] = i;
    }
  }

  const size_t C1 = SZ_W1T / 8, C2 = C1 + SZ_W2T / 8, C3 = C2 + SZ_X / 8,
               C4 = C3 + SZ_W1C / 8, C5 = C4 + SZ_W2C / 8;
  for (size_t i = (size_t)blockIdx.x * blockDim.x + threadIdx.x; i < C5;
       i += (size_t)gridDim.x * blockDim.x) {
    const float* s; size_t doff;
    if (i < C1)      { s = w1t + i * 8;        doff = OFF_W1T + i * 8; }
    else if (i < C2) { s = w2t + (i - C1) * 8; doff = OFF_W2T + (i - C1) * 8; }
    else if (i < C3) { s = x   + (i - C2) * 8; doff = OFF_X   + (i - C2) * 8; }
    else if (i < C4) { s = w1c + (i - C3) * 8; doff = OFF_W1C + (i - C3) * 8; }
    else             { s = w2c + (i - C4) * 8; doff = OFF_W2C + (i - C4) * 8; }
    *(bf16x8*)(wsb + doff) = ld_gfrag(s);
  }
}

// ---------------- Kernel A (64 e per wave, MFMA1 double-buffered) ----------------
// grid = 768*2. logical L (XCD-chunked): sid = L>>1 -> chain = order[sid], eblk = L&1.
template <bool PP>
__global__ __launch_bounds__(256) void mixer_h_kernel(
    const float* __restrict__ x, const int* __restrict__ eidx,
    const float* __restrict__ w1t, const float* __restrict__ w1c, const float* __restrict__ b1,
    const short* __restrict__ wsb, const int* __restrict__ order, short* __restrict__ hws) {
  __shared__ __align__(16) char smem[SMA_TOTAL];
  const int L = xcd_chunk(blockIdx.x, NCHAIN * 2);
  const int sid = L >> 1, eblk = L & 1;
  const int bhk = PP ? order[sid] : sid;
  const int h = (bhk >> 1) % NHEAD;
  const int tid = threadIdx.x, w = tid >> 6, lane = tid & 63, lr = lane & 15, lg = lane >> 4;

  const int e = eidx[bhk];
  const size_t eh = (size_t)e * NHEAD + h;
  short* H = hws + (size_t)bhk * HDIM * HIDD;
  const float* B1f = b1 + eh * HDIM * HIDD;

  const int e0 = eblk * 256 + w * 64;

  // MFMA1: T1[d][e] = sum_n X[d,n]*W1t[e,n];  A=X (m=d), B=W1t (n=e), k=n
  // Explicit 2-stage pipeline: load ks+1's 8 frags before ks's 16 MFMAs.
  f32x4 acc1[4][4];  // [et][dt]
  #pragma unroll
  for (int et = 0; et < 4; ++et)
    #pragma unroll
    for (int dt = 0; dt < 4; ++dt) acc1[et][dt] = (f32x4){0.f, 0.f, 0.f, 0.f};

  bf16x8 wfr[2][4], xfr[2][4];
  auto loadA = [&](int ks, int buf) {
    #pragma unroll
    for (int et = 0; et < 4; ++et) {
      if (PP) wfr[buf][et] = *(const bf16x8*)(wsb + OFF_W1T + eh * HIDD * NTOK +
                                              (size_t)(e0 + et * 16 + lr) * NTOK + ks * 32 + lg * 8);
      else    wfr[buf][et] = ld_gfrag(w1t + eh * HIDD * NTOK +
                                      (size_t)(e0 + et * 16 + lr) * NTOK + ks * 32 + lg * 8);
    }
    #pragma unroll
    for (int dt = 0; dt < 4; ++dt) {
      if (PP) xfr[buf][dt] = *(const bf16x8*)(wsb + OFF_X + (size_t)(bhk >> 1) * HDIM * NTOK +
                                              (size_t)(dt * 16 + lr) * NTOK + ks * 32 + lg * 8);
      else    xfr[buf][dt] = ld_gfrag(x + (size_t)(bhk >> 1) * HDIM * NTOK +
                                      (size_t)(dt * 16 + lr) * NTOK + ks * 32 + lg * 8);
    }
  };
  loadA(0, 0);
  #pragma unroll
  for (int ks = 0; ks < 8; ++ks) {
    const int cur = ks & 1;
    if (ks < 7) loadA(ks + 1, cur ^ 1);
    #pragma unroll
    for (int dt = 0; dt < 4; ++dt)
      #pragma unroll
      for (int et = 0; et < 4; ++et)
        acc1[et][dt] = MFMA16(xfr[cur][dt], wfr[cur][et], acc1[et][dt]);
  }

  // relayout T1^T via wave-private LDS (col=e=lr, row=d=dt*16+lg*4+i) -> [e][d]
  char* t1 = smem + w * T1_W;
  #pragma unroll
  for (int et = 0; et < 4; ++et)
    #pragma unroll
    for (int dt = 0; dt < 4; ++dt) {
      bf16x4 p;
      #pragma unroll
      for (int i = 0; i < 4; ++i) p[i] = f2bf(acc1[et][dt][i]);
      *(bf16x4*)(t1 + (et * 16 + lr) * P_T1 + (dt * 16 + lg * 4) * 2) = p;
    }

  // MFMA2: T2^T[e][c] = sum_d T1^T[e,d]*W1c[c,d] + B1;  D: col=c=lr, row=e=lg*4+i
  f32x4 acc2[4][4];  // [et][ct]
  #pragma unroll
  for (int et = 0; et < 4; ++et)
    #pragma unroll
    for (int ct = 0; ct < 4; ++ct)
      acc2[et][ct] = *(const f32x4*)(B1f + (size_t)(ct * 16 + lr) * HIDD + e0 + et * 16 + lg * 4);
  #pragma unroll
  for (int ks = 0; ks < 2; ++ks) {
    bf16x8 a[4];
    #pragma unroll
    for (int et = 0; et < 4; ++et)
      a[et] = *(const bf16x8*)(t1 + (et * 16 + lr) * P_T1 + (ks * 32 + lg * 8) * 2);
    #pragma unroll
    for (int ct = 0; ct < 4; ++ct) {
      bf16x8 bfr;
      if (PP) bfr = *(const bf16x8*)(wsb + OFF_W1C + eh * HDIM * HDIM +
                                     (size_t)(ct * 16 + lr) * HDIM + ks * 32 + lg * 8);
      else    bfr = ld_gfrag(w1c + eh * HDIM * HDIM +
                             (size_t)(ct * 16 + lr) * HDIM + ks * 32 + lg * 8);
      #pragma unroll
      for (int et = 0; et < 4; ++et) acc2[et][ct] = MFMA16(a[et], bfr, acc2[et][ct]);
    }
  }

  // GELU + store H[c][e] (col=c=lr, row=e=lg*4+i)
  #pragma unroll
  for (int et = 0; et < 4; ++et)
    #pragma unroll
    for (int ct = 0; ct < 4; ++ct) {
      bf16x4 g;
      #pragma unroll
      for (int i = 0; i < 4; ++i) g[i] = f2bf(gelu_fast(acc2[et][ct][i]));
      *(bf16x4*)(H + (size_t)(ct * 16 + lr) * HIDD + e0 + et * 16 + lg * 4) = g;
    }
}

// ---------------- Kernel B v6 (64c x 64n per wave, MFMA3 double-buffered) ----------------
// grid = 768 x 256. L = xcd_chunk(bx, 768): sid = L>>1 -> bh = order2[sid], nhalf = L&1.
// Wave w: kk = w>>1, wq = w&1; n rows [nhalf*128 + wq*64, +64). k=1 waves publish
// weighted partials via LDS (aliases dead t3), k=0 waves combine + plain f32 stores.
template <bool PP>
__global__ __launch_bounds__(256) void mixer_out_kernel(
    const int* __restrict__ eidx, const float* __restrict__ ewt,
    const float* __restrict__ w2t, const float* __restrict__ w2c, const float* __restrict__ b2,
    const short* __restrict__ wsb, const int* __restrict__ order2,
    const short* __restrict__ hws, float* __restrict__ out) {
  __shared__ __align__(16) char smem[SMB_TOTAL];
  const int L = xcd_chunk(blockIdx.x, NBH * 2);
  const int sid = L >> 1, nhalf = L & 1;
  const int bh = PP ? order2[sid] : sid;
  const int h = bh % NHEAD;
  const int tid = threadIdx.x, w = tid >> 6, lane = tid & 63, lr = lane & 15, lg = lane >> 4;
  const int kk = w >> 1, wq = w & 1;
  const int nb = nhalf * 128 + wq * 64;
  char* t3 = smem + w * T3_W;
  float* OUT = out + (size_t)bh * HDIM * NTOK;

  const int e = eidx[bh * TOPK + kk];
  const float wk = ewt[bh * TOPK + kk];
  const size_t eh = (size_t)e * NHEAD + h;
  const short* Hk = hws + (size_t)(bh * TOPK + kk) * HDIM * HIDD;
  const float* B2f = b2 + eh * HDIM * NTOK;

  // MFMA3: T3[c][n] = sum_e H[c,e]*W2t[n,e];  A=H (m=c), B=W2t (n=n), k=e
  // Explicit 2-stage pipeline.
  f32x4 acc3[4][4];  // [ct][nt]
  #pragma unroll
  for (int ct = 0; ct < 4; ++ct)
    #pragma unroll
    for (int nt = 0; nt < 4; ++nt) acc3[ct][nt] = (f32x4){0.f, 0.f, 0.f, 0.f};

  bf16x8 ha[2][4], wb[2][4];
  auto loadB = [&](int ks, int buf) {
    #pragma unroll
    for (int ct = 0; ct < 4; ++ct)
      ha[buf][ct] = *(const bf16x8*)(Hk + (size_t)(ct * 16 + lr) * HIDD + ks * 32 + lg * 8);
    #pragma unroll
    for (int nt = 0; nt < 4; ++nt) {
      if (PP) wb[buf][nt] = *(const bf16x8*)(wsb + OFF_W2T + eh * NTOK * HIDD +
                                             (size_t)(nb + nt * 16 + lr) * HIDD + ks * 32 + lg * 8);
      else    wb[buf][nt] = ld_gfrag(w2t + eh * NTOK * HIDD +
                                     (size_t)(nb + nt * 16 + lr) * HIDD + ks * 32 + lg * 8);
    }
  };
  loadB(0, 0);
  #pragma unroll
  for (int ks = 0; ks < 16; ++ks) {
    const int cur = ks & 1;
    if (ks < 15) loadB(ks + 1, cur ^ 1);
    #pragma unroll
    for (int nt = 0; nt < 4; ++nt)
      #pragma unroll
      for (int ct = 0; ct < 4; ++ct) acc3[ct][nt] = MFMA16(ha[cur][ct], wb[cur][nt], acc3[ct][nt]);
  }

  // relayout T3^T via wave-private LDS (col=n=lr, row=c=ct*16+lg*4+i) -> [n][c]
  #pragma unroll
  for (int ct = 0; ct < 4; ++ct)
    #pragma unroll
    for (int nt = 0; nt < 4; ++nt) {
      bf16x4 p;
      #pragma unroll
      for (int i = 0; i < 4; ++i) p[i] = f2bf(acc3[ct][nt][i]);
      *(bf16x4*)(t3 + (nt * 16 + lr) * P_T3 + (ct * 16 + lg * 4) * 2) = p;
    }

  // MFMA4: OUT^T[n][co] = sum_c T3^T[n,c]*W2c[co,c]
  f32x4 acc4[4][4];  // [nt][cot]
  #pragma unroll
  for (int nt = 0; nt < 4; ++nt)
    #pragma unroll
    for (int ct = 0; ct < 4; ++ct) acc4[nt][ct] = (f32x4){0.f, 0.f, 0.f, 0.f};
  #pragma unroll
  for (int ks = 0; ks < 2; ++ks) {
    bf16x8 a[4];
    #pragma unroll
    for (int nt = 0; nt < 4; ++nt)
      a[nt] = *(const bf16x8*)(t3 + (nt * 16 + lr) * P_T3 + (ks * 32 + lg * 8) * 2);
    #pragma unroll
    for (int ct = 0; ct < 4; ++ct) {
      bf16x8 bfr;
      if (PP) bfr = *(const bf16x8*)(wsb + OFF_W2C + eh * HDIM * HDIM +
                                     (size_t)(ct * 16 + lr) * HDIM + ks * 32 + lg * 8);
      else    bfr = ld_gfrag(w2c + eh * HDIM * HDIM +
                             (size_t)(ct * 16 + lr) * HDIM + ks * 32 + lg * 8);
      #pragma unroll
      for (int nt = 0; nt < 4; ++nt) acc4[nt][ct] = MFMA16(a[nt], bfr, acc4[nt][ct]);
    }
  }

  // weighted partial in place: acc4 = wk*(acc4 + B2)  (col=co=lr, row=n=lg*4+i)
  #pragma unroll
  for (int nt = 0; nt < 4; ++nt)
    #pragma unroll
    for (int cot = 0; cot < 4; ++cot) {
      const int co = cot * 16 + lr;
      const int n0 = nb + nt * 16 + lg * 4;
      f32x4 bb = *(const f32x4*)(B2f + (size_t)co * NTOK + n0);
      #pragma unroll
      for (int i = 0; i < 4; ++i) acc4[nt][cot][i] = wk * (acc4[nt][cot][i] + bb[i]);
    }

  __syncthreads();  // all waves done reading their t3 (comb aliases t3 region)

  // k=1 waves publish partials: comb[wq] = [64 n][64 co] f32 at offset wq*16384
  if (kk == 1) {
    float* comb = (float*)(smem + wq * 16384);
    #pragma unroll
    for (int nt = 0; nt < 4; ++nt)
      #pragma unroll
      for (int cot = 0; cot < 4; ++cot) {
        const int co = cot * 16 + lr;
        #pragma unroll
        for (int i = 0; i < 4; ++i)
          comb[(nt * 16 + lg * 4 + i) * 64 + co] = acc4[nt][cot][i];
      }
  }
  __syncthreads();

  // k=0 waves combine + store (each (co,n) written exactly once across the grid)
  if (kk == 0) {
    const float* comb = (const float*)(smem + wq * 16384);
    #pragma unroll
    for (int nt = 0; nt < 4; ++nt)
      #pragma unroll
      for (int cot = 0; cot < 4; ++cot) {
        const int co = cot * 16 + lr;
        const int n0 = nb + nt * 16 + lg * 4;
        f32x4 v;
        #pragma unroll
        for (int i = 0; i < 4; ++i)
          v[i] = acc4[nt][cot][i] + comb[(nt * 16 + lg * 4 + i) * 64 + co];
        *(f32x4*)(OUT + (size_t)co * NTOK + n0) = v;
      }
  }
}

extern "C" void kernel_launch(void* const* d_in, const int* in_sizes, int n_in,
                              void* d_out, int out_size, void* d_ws, size_t ws_size,
                              hipStream_t stream) {
  const float* x   = (const float*)d_in[0];
  const int*   ei  = (const int*)d_in[1];
  const float* ew  = (const float*)d_in[2];
  const float* w1t = (const float*)d_in[3];
  const float* w1c = (const float*)d_in[4];
  const float* b1  = (const float*)d_in[5];
  const float* w2t = (const float*)d_in[6];
  const float* w2c = (const float*)d_in[7];
  const float* b2  = (const float*)d_in[8];
  float* out = (float*)d_out;
  short* wsb = (short*)d_ws;
  short* hws = wsb + OFF_H;
  int* order  = (int*)(wsb + TOTEL);
  int* order2 = order + NCHAIN;

  if (ws_size >= NEED) {
    prepack_sort_kernel<<<dim3(2048), dim3(256), 0, stream>>>(
        w1t, w2t, x, w1c, w2c, wsb, ei, order, order2);
    mixer_h_kernel<true><<<dim3(NCHAIN * 2), dim3(256), 0, stream>>>(
        x, ei, w1t, w1c, b1, wsb, order, hws);
    mixer_out_kernel<true><<<dim3(NBH * 2), dim3(256), 0, stream>>>(
        ei, ew, w2t, w2c, b2, wsb, order2, hws, out);
  } else {
    mixer_h_kernel<false><<<dim3(NCHAIN * 2), dim3(256), 0, stream>>>(
        x, ei, w1t, w1c, b1, wsb, order, hws);
    mixer_out_kernel<false><<<dim3(NBH * 2), dim3(256), 0, stream>>>(
        ei, ew, w2t, w2c, b2, wsb, order2, hws, out);
  }
}

// Round 18
// 165.610 us; speedup vs baseline: 1.0212x; 1.0212x over previous
//
#include <hip/hip_runtime.h>
#include <hip/hip_bf16.h>

// MultiHeadBatchedMixers, group-sorted two-kernel structure (no atomics):
//   prepack+sort: w1t,w2t,x,w1c,w2c -> bf16 ws (biases stay f32; L2-hot);
//                 block 0 builds order[768] (by (e,h)) / order2[384] (by (e0,h))
//   Kernel A (grid 1536 x 128thr = 2 waves, XCD-chunked, group-ordered):
//       H = GELU(W1c @ X @ W1t^T + B1); wave owns 128 e (intensity 2.67)
//   Kernel B (grid 768x256, XCD-chunked, group-ordered): 4 waves = 2 k x 2 wq,
//       wave owns 64c x 64n (intensity 2); LDS combine; plain f32 stores
// bf16 MFMA 16x16x32, f32 accumulate.
// NOTE (R8/R10): VGPR+AGPR share one file on gfx950; never min-waves-bound the
// MFMA kernels (reg cap -> accumulator spill -> WRITE blowup).
// NOTE (R12/R13/R14/R18): cost tracks TOTAL load instructions & MFMA/load intensity;
// occupancy (10-30%) and explicit double-buffering (R17) are both non-factors.
// NOTE (R15): never split accumulator lifetimes within a wave tile (serializes).

namespace {
constexpr int NHEAD = 12, NTOK = 256, HDIM = 64, HIDD = 512, NBATCH = 32, TOPK = 2;
constexpr int NCHAIN = NBATCH * NHEAD * TOPK;  // 768
constexpr int NBH = NBATCH * NHEAD;            // 384
constexpr int NGROUP = 8 * NHEAD;              // 96

// Kernel A LDS: per-wave T1^T [128 e][64 d] bf16, pitch +16B; 2 waves
constexpr int P_T1 = HDIM * 2 + 16;   // 144
constexpr int T1_W = 128 * P_T1;      // 18432
constexpr int SMA_TOTAL = 2 * T1_W;   // 36864
// Kernel B LDS: per-wave T3^T [64 n][64 c] (4 waves); combine aliases [0,32768)
constexpr int P_T3 = HDIM * 2 + 16;   // 144
constexpr int T3_W = 64 * P_T3;       // 9216
constexpr int SMB_TOTAL = 4 * T3_W;   // 36864

// ws layout: [H][w1t][w2t][x][b1(unused)][b2(unused)][w1c][w2c] bf16, then orders
constexpr size_t SZ_H    = (size_t)NCHAIN * HDIM * HIDD;          // 25,165,824
constexpr size_t OFF_H   = 0;
constexpr size_t OFF_W1T = OFF_H + SZ_H;
constexpr size_t SZ_W1T  = (size_t)8 * NHEAD * HIDD * NTOK;       // 12,582,912
constexpr size_t OFF_W2T = OFF_W1T + SZ_W1T;
constexpr size_t SZ_W2T  = (size_t)8 * NHEAD * NTOK * HIDD;
constexpr size_t OFF_X   = OFF_W2T + SZ_W2T;
constexpr size_t SZ_X    = (size_t)NBATCH * NHEAD * HDIM * NTOK;  // 6,291,456
constexpr size_t OFF_B1  = OFF_X + SZ_X;
constexpr size_t SZ_B1   = (size_t)8 * NHEAD * HDIM * HIDD;
constexpr size_t OFF_B2  = OFF_B1 + SZ_B1;
constexpr size_t SZ_B2   = (size_t)8 * NHEAD * HDIM * NTOK;
constexpr size_t OFF_W1C = OFF_B2 + SZ_B2;
constexpr size_t SZ_W1C  = (size_t)8 * NHEAD * HDIM * HDIM;       // 393,216
constexpr size_t OFF_W2C = OFF_W1C + SZ_W1C;
constexpr size_t SZ_W2C  = (size_t)8 * NHEAD * HDIM * HDIM;
constexpr size_t TOTEL   = OFF_W2C + SZ_W2C;                      // shorts
constexpr size_t NEED    = TOTEL * 2 + (NCHAIN + NBH) * 4;
}

typedef float f32x4 __attribute__((ext_vector_type(4)));
typedef short bf16x8 __attribute__((ext_vector_type(8)));
typedef short bf16x4 __attribute__((ext_vector_type(4)));

#define MFMA16(a, b, c) __builtin_amdgcn_mfma_f32_16x16x32_bf16((a), (b), (c), 0, 0, 0)

__device__ __forceinline__ short f2bf(float f) {
  union { float f; unsigned u; } v; v.f = f;
  unsigned r = v.u + 0x7fffu + ((v.u >> 16) & 1u);
  return (short)(r >> 16);
}

__device__ __forceinline__ bf16x8 ld_gfrag(const float* p) {
  float4 a = *(const float4*)p;
  float4 b = *(const float4*)(p + 4);
  bf16x8 r;
  r[0] = f2bf(a.x); r[1] = f2bf(a.y); r[2] = f2bf(a.z); r[3] = f2bf(a.w);
  r[4] = f2bf(b.x); r[5] = f2bf(b.y); r[6] = f2bf(b.z); r[7] = f2bf(b.w);
  return r;
}

// gelu(x) = x * rcp(1 + exp2(-2.30220826 * x * (1 + 0.044715 x^2)))  [err ~1e-7 << bf16]
__device__ __forceinline__ float gelu_fast(float x) {
  float arg = -2.30220826f * x * __builtin_fmaf(0.044715f, x * x, 1.0f);
  float e = __builtin_amdgcn_exp2f(arg);
  return x * __builtin_amdgcn_rcpf(1.0f + e);
}

// XCD-chunk swizzle (nwg % 8 == 0): logical sequence contiguous per XCD.
__device__ __forceinline__ int xcd_chunk(int bx, int nwg) {
  return (bx & 7) * (nwg >> 3) + (bx >> 3);
}

// ---------------- Prepack (+ block-0 group sort); biases NOT converted ----------------
__global__ __launch_bounds__(256) void prepack_sort_kernel(
    const float* __restrict__ w1t, const float* __restrict__ w2t,
    const float* __restrict__ x, const float* __restrict__ w1c,
    const float* __restrict__ w2c, short* __restrict__ wsb,
    const int* __restrict__ eidx, int* __restrict__ order, int* __restrict__ order2) {
  if (blockIdx.x == 0) {
    __shared__ int keys[NCHAIN];
    __shared__ int keys2[NBH];
    __shared__ int cnt[NGROUP + 1];
    __shared__ int cnt2[NGROUP + 1];
    const int t = threadIdx.x;
    for (int i = t; i <= NGROUP; i += 256) { cnt[i] = 0; cnt2[i] = 0; }
    __syncthreads();
    for (int i = t; i < NCHAIN; i += 256) {
      int h = (i >> 1) % NHEAD;
      int key = eidx[i] * NHEAD + h;
      keys[i] = key;
      atomicAdd(&cnt[key + 1], 1);
    }
    for (int i = t; i < NBH; i += 256) {
      int h = i % NHEAD;
      int key = eidx[i * TOPK] * NHEAD + h;
      keys2[i] = key;
      atomicAdd(&cnt2[key + 1], 1);
    }
    __syncthreads();
    if (t == 0) for (int i = 1; i <= NGROUP; ++i) cnt[i] += cnt[i - 1];
    if (t == 1) for (int i = 1; i <= NGROUP; ++i) cnt2[i] += cnt2[i - 1];
    __syncthreads();
    for (int i = t; i < NCHAIN; i += 256) {
      int pos = atomicAdd(&cnt[keys[i]], 1);  // rank within group (order-agnostic downstream)
      order[pos] = i;
    }
    for (int i = t; i < NBH; i += 256) {
      int pos = atomicAdd(&cnt2[keys2[i]], 1);
      order2[pos] = i;
    }
  }

  const size_t C1 = SZ_W1T / 8, C2 = C1 + SZ_W2T / 8, C3 = C2 + SZ_X / 8,
               C4 = C3 + SZ_W1C / 8, C5 = C4 + SZ_W2C / 8;
  for (size_t i = (size_t)blockIdx.x * blockDim.x + threadIdx.x; i < C5;
       i += (size_t)gridDim.x * blockDim.x) {
    const float* s; size_t doff;
    if (i < C1)      { s = w1t + i * 8;        doff = OFF_W1T + i * 8; }
    else if (i < C2) { s = w2t + (i - C1) * 8; doff = OFF_W2T + (i - C1) * 8; }
    else if (i < C3) { s = x   + (i - C2) * 8; doff = OFF_X   + (i - C2) * 8; }
    else if (i < C4) { s = w1c + (i - C3) * 8; doff = OFF_W1C + (i - C3) * 8; }
    else             { s = w2c + (i - C4) * 8; doff = OFF_W2C + (i - C4) * 8; }
    *(bf16x8*)(wsb + doff) = ld_gfrag(s);
  }
}

// ---------------- Kernel A v5 (128 e per wave, 2 waves/block) ----------------
// grid = 1536 x 128 threads. L = xcd_chunk(bx,1536): sid = L>>1 -> chain = order[sid],
// eblk = L&1. Wave w in {0,1} owns e = eblk*256 + w*128 .. +128. Intensity 2.67.
template <bool PP>
__global__ __launch_bounds__(128) void mixer_h_kernel(
    const float* __restrict__ x, const int* __restrict__ eidx,
    const float* __restrict__ w1t, const float* __restrict__ w1c, const float* __restrict__ b1,
    const short* __restrict__ wsb, const int* __restrict__ order, short* __restrict__ hws) {
  __shared__ __align__(16) char smem[SMA_TOTAL];
  const int L = xcd_chunk(blockIdx.x, NCHAIN * 2);
  const int sid = L >> 1, eblk = L & 1;
  const int bhk = PP ? order[sid] : sid;
  const int h = (bhk >> 1) % NHEAD;
  const int tid = threadIdx.x, w = tid >> 6, lane = tid & 63, lr = lane & 15, lg = lane >> 4;

  const int e = eidx[bhk];
  const size_t eh = (size_t)e * NHEAD + h;
  short* H = hws + (size_t)bhk * HDIM * HIDD;
  const float* B1f = b1 + eh * HDIM * HIDD;

  const int e0 = eblk * 256 + w * 128;

  // MFMA1: T1[d][e] = sum_n X[d,n]*W1t[e,n];  A=X (m=d), B=W1t (n=e), k=n
  // Per ks: 8 W1T loads + 4 X loads -> 32 MFMAs (intensity 2.67).
  f32x4 acc1[8][4];  // [et][dt]
  #pragma unroll
  for (int et = 0; et < 8; ++et)
    #pragma unroll
    for (int dt = 0; dt < 4; ++dt) acc1[et][dt] = (f32x4){0.f, 0.f, 0.f, 0.f};
  #pragma unroll
  for (int ks = 0; ks < 8; ++ks) {
    bf16x8 wfr[8];
    #pragma unroll
    for (int et = 0; et < 8; ++et) {
      if (PP) wfr[et] = *(const bf16x8*)(wsb + OFF_W1T + eh * HIDD * NTOK +
                                         (size_t)(e0 + et * 16 + lr) * NTOK + ks * 32 + lg * 8);
      else    wfr[et] = ld_gfrag(w1t + eh * HIDD * NTOK +
                                 (size_t)(e0 + et * 16 + lr) * NTOK + ks * 32 + lg * 8);
    }
    #pragma unroll
    for (int dt = 0; dt < 4; ++dt) {
      bf16x8 xfr;
      if (PP) xfr = *(const bf16x8*)(wsb + OFF_X + (size_t)(bhk >> 1) * HDIM * NTOK +
                                     (size_t)(dt * 16 + lr) * NTOK + ks * 32 + lg * 8);
      else    xfr = ld_gfrag(x + (size_t)(bhk >> 1) * HDIM * NTOK +
                             (size_t)(dt * 16 + lr) * NTOK + ks * 32 + lg * 8);
      #pragma unroll
      for (int et = 0; et < 8; ++et) acc1[et][dt] = MFMA16(xfr, wfr[et], acc1[et][dt]);
    }
  }

  // relayout T1^T via wave-private LDS (col=e=lr, row=d=dt*16+lg*4+i) -> [e][d]
  char* t1 = smem + w * T1_W;
  #pragma unroll
  for (int et = 0; et < 8; ++et)
    #pragma unroll
    for (int dt = 0; dt < 4; ++dt) {
      bf16x4 p;
      #pragma unroll
      for (int i = 0; i < 4; ++i) p[i] = f2bf(acc1[et][dt][i]);
      *(bf16x4*)(t1 + (et * 16 + lr) * P_T1 + (dt * 16 + lg * 4) * 2) = p;
    }

  // MFMA2: T2^T[e][c] = sum_d T1^T[e,d]*W1c[c,d] + B1;  D: col=c=lr, row=e=lg*4+i
  f32x4 acc2[8][4];  // [et][ct]  (acc1 dead -> regs reused)
  #pragma unroll
  for (int et = 0; et < 8; ++et)
    #pragma unroll
    for (int ct = 0; ct < 4; ++ct)
      acc2[et][ct] = *(const f32x4*)(B1f + (size_t)(ct * 16 + lr) * HIDD + e0 + et * 16 + lg * 4);
  #pragma unroll
  for (int ks = 0; ks < 2; ++ks) {
    bf16x8 a[8];
    #pragma unroll
    for (int et = 0; et < 8; ++et)
      a[et] = *(const bf16x8*)(t1 + (et * 16 + lr) * P_T1 + (ks * 32 + lg * 8) * 2);
    #pragma unroll
    for (int ct = 0; ct < 4; ++ct) {
      bf16x8 bfr;
      if (PP) bfr = *(const bf16x8*)(wsb + OFF_W1C + eh * HDIM * HDIM +
                                     (size_t)(ct * 16 + lr) * HDIM + ks * 32 + lg * 8);
      else    bfr = ld_gfrag(w1c + eh * HDIM * HDIM +
                             (size_t)(ct * 16 + lr) * HDIM + ks * 32 + lg * 8);
      #pragma unroll
      for (int et = 0; et < 8; ++et) acc2[et][ct] = MFMA16(a[et], bfr, acc2[et][ct]);
    }
  }

  // GELU + store H[c][e] (col=c=lr, row=e=lg*4+i)
  #pragma unroll
  for (int et = 0; et < 8; ++et)
    #pragma unroll
    for (int ct = 0; ct < 4; ++ct) {
      bf16x4 g;
      #pragma unroll
      for (int i = 0; i < 4; ++i) g[i] = f2bf(gelu_fast(acc2[et][ct][i]));
      *(bf16x4*)(H + (size_t)(ct * 16 + lr) * HIDD + e0 + et * 16 + lg * 4) = g;
    }
}

// ---------------- Kernel B v6 (64c x 64n per wave, intensity 2; R16 form) ----------------
// grid = 768 x 256. L = xcd_chunk(bx, 768): sid = L>>1 -> bh = order2[sid], nhalf = L&1.
// Wave w: kk = w>>1, wq = w&1; n rows [nhalf*128 + wq*64, +64). k=1 waves publish
// weighted partials via LDS (aliases dead t3), k=0 waves combine + plain f32 stores.
template <bool PP>
__global__ __launch_bounds__(256) void mixer_out_kernel(
    const int* __restrict__ eidx, const float* __restrict__ ewt,
    const float* __restrict__ w2t, const float* __restrict__ w2c, const float* __restrict__ b2,
    const short* __restrict__ wsb, const int* __restrict__ order2,
    const short* __restrict__ hws, float* __restrict__ out) {
  __shared__ __align__(16) char smem[SMB_TOTAL];
  const int L = xcd_chunk(blockIdx.x, NBH * 2);
  const int sid = L >> 1, nhalf = L & 1;
  const int bh = PP ? order2[sid] : sid;
  const int h = bh % NHEAD;
  const int tid = threadIdx.x, w = tid >> 6, lane = tid & 63, lr = lane & 15, lg = lane >> 4;
  const int kk = w >> 1, wq = w & 1;
  const int nb = nhalf * 128 + wq * 64;
  char* t3 = smem + w * T3_W;
  float* OUT = out + (size_t)bh * HDIM * NTOK;

  const int e = eidx[bh * TOPK + kk];
  const float wk = ewt[bh * TOPK + kk];
  const size_t eh = (size_t)e * NHEAD + h;
  const short* Hk = hws + (size_t)(bh * TOPK + kk) * HDIM * HIDD;
  const float* B2f = b2 + eh * HDIM * NTOK;

  // MFMA3: T3[c][n] = sum_e H[c,e]*W2t[n,e];  A=H (m=c), B=W2t (n=n), k=e
  f32x4 acc3[4][4];  // [ct][nt]
  #pragma unroll
  for (int ct = 0; ct < 4; ++ct)
    #pragma unroll
    for (int nt = 0; nt < 4; ++nt) acc3[ct][nt] = (f32x4){0.f, 0.f, 0.f, 0.f};
  #pragma unroll 4
  for (int ks = 0; ks < 16; ++ks) {
    bf16x8 a[4];
    #pragma unroll
    for (int ct = 0; ct < 4; ++ct)
      a[ct] = *(const bf16x8*)(Hk + (size_t)(ct * 16 + lr) * HIDD + ks * 32 + lg * 8);
    #pragma unroll
    for (int nt = 0; nt < 4; ++nt) {
      bf16x8 bfr;
      if (PP) bfr = *(const bf16x8*)(wsb + OFF_W2T + eh * NTOK * HIDD +
                                     (size_t)(nb + nt * 16 + lr) * HIDD + ks * 32 + lg * 8);
      else    bfr = ld_gfrag(w2t + eh * NTOK * HIDD +
                             (size_t)(nb + nt * 16 + lr) * HIDD + ks * 32 + lg * 8);
      #pragma unroll
      for (int ct = 0; ct < 4; ++ct) acc3[ct][nt] = MFMA16(a[ct], bfr, acc3[ct][nt]);
    }
  }

  // relayout T3^T via wave-private LDS (col=n=lr, row=c=ct*16+lg*4+i) -> [n][c]
  #pragma unroll
  for (int ct = 0; ct < 4; ++ct)
    #pragma unroll
    for (int nt = 0; nt < 4; ++nt) {
      bf16x4 p;
      #pragma unroll
      for (int i = 0; i < 4; ++i) p[i] = f2bf(acc3[ct][nt][i]);
      *(bf16x4*)(t3 + (nt * 16 + lr) * P_T3 + (ct * 16 + lg * 4) * 2) = p;
    }

  // MFMA4: OUT^T[n][co] = sum_c T3^T[n,c]*W2c[co,c]
  f32x4 acc4[4][4];  // [nt][cot]
  #pragma unroll
  for (int nt = 0; nt < 4; ++nt)
    #pragma unroll
    for (int ct = 0; ct < 4; ++ct) acc4[nt][ct] = (f32x4){0.f, 0.f, 0.f, 0.f};
  #pragma unroll
  for (int ks = 0; ks < 2; ++ks) {
    bf16x8 a[4];
    #pragma unroll
    for (int nt = 0; nt < 4; ++nt)
      a[nt] = *(const bf16x8*)(t3 + (nt * 16 + lr) * P_T3 + (ks * 32 + lg * 8) * 2);
    #pragma unroll
    for (int ct = 0; ct < 4; ++ct) {
      bf16x8 bfr;
      if (PP) bfr = *(const bf16x8*)(wsb + OFF_W2C + eh * HDIM * HDIM +
                                     (size_t)(ct * 16 + lr) * HDIM + ks * 32 + lg * 8);
      else    bfr = ld_gfrag(w2c + eh * HDIM * HDIM +
                             (size_t)(ct * 16 + lr) * HDIM + ks * 32 + lg * 8);
      #pragma unroll
      for (int nt = 0; nt < 4; ++nt) acc4[nt][ct] = MFMA16(a[nt], bfr, acc4[nt][ct]);
    }
  }

  // weighted partial in place: acc4 = wk*(acc4 + B2)  (col=co=lr, row=n=lg*4+i)
  #pragma unroll
  for (int nt = 0; nt < 4; ++nt)
    #pragma unroll
    for (int cot = 0; cot < 4; ++cot) {
      const int co = cot * 16 + lr;
      const int n0 = nb + nt * 16 + lg * 4;
      f32x4 bb = *(const f32x4*)(B2f + (size_t)co * NTOK + n0);
      #pragma unroll
      for (int i = 0; i < 4; ++i) acc4[nt][cot][i] = wk * (acc4[nt][cot][i] + bb[i]);
    }

  __syncthreads();  // all waves done reading their t3 (comb aliases t3 region)

  // k=1 waves publish partials: comb[wq] = [64 n][64 co] f32 at offset wq*16384
  if (kk == 1) {
    float* comb = (float*)(smem + wq * 16384);
    #pragma unroll
    for (int nt = 0; nt < 4; ++nt)
      #pragma unroll
      for (int cot = 0; cot < 4; ++cot) {
        const int co = cot * 16 + lr;
        #pragma unroll
        for (int i = 0; i < 4; ++i)
          comb[(nt * 16 + lg * 4 + i) * 64 + co] = acc4[nt][cot][i];
      }
  }
  __syncthreads();

  // k=0 waves combine + store (each (co,n) written exactly once across the grid)
  if (kk == 0) {
    const float* comb = (const float*)(smem + wq * 16384);
    #pragma unroll
    for (int nt = 0; nt < 4; ++nt)
      #pragma unroll
      for (int cot = 0; cot < 4; ++cot) {
        const int co = cot * 16 + lr;
        const int n0 = nb + nt * 16 + lg * 4;
        f32x4 v;
        #pragma unroll
        for (int i = 0; i < 4; ++i)
          v[i] = acc4[nt][cot][i] + comb[(nt * 16 + lg * 4 + i) * 64 + co];
        *(f32x4*)(OUT + (size_t)co * NTOK + n0) = v;
      }
  }
}

extern "C" void kernel_launch(void* const* d_in, const int* in_sizes, int n_in,
                              void* d_out, int out_size, void* d_ws, size_t ws_size,
                              hipStream_t stream) {
  const float* x   = (const float*)d_in[0];
  const int*   ei  = (const int*)d_in[1];
  const float* ew  = (const float*)d_in[2];
  const float* w1t = (const float*)d_in[3];
  const float* w1c = (const float*)d_in[4];
  const float* b1  = (const float*)d_in[5];
  const float* w2t = (const float*)d_in[6];
  const float* w2c = (const float*)d_in[7];
  const float* b2  = (const float*)d_in[8];
  float* out = (float*)d_out;
  short* wsb = (short*)d_ws;
  short* hws = wsb + OFF_H;
  int* order  = (int*)(wsb + TOTEL);
  int* order2 = order + NCHAIN;

  if (ws_size >= NEED) {
    prepack_sort_kernel<<<dim3(2048), dim3(256), 0, stream>>>(
        w1t, w2t, x, w1c, w2c, wsb, ei, order, order2);
    mixer_h_kernel<true><<<dim3(NCHAIN * 2), dim3(128), 0, stream>>>(
        x, ei, w1t, w1c, b1, wsb, order, hws);
    mixer_out_kernel<true><<<dim3(NBH * 2), dim3(256), 0, stream>>>(
        ei, ew, w2t, w2c, b2, wsb, order2, hws, out);
  } else {
    mixer_h_kernel<false><<<dim3(NCHAIN * 2), dim3(128), 0, stream>>>(
        x, ei, w1t, w1c, b1, wsb, order, hws);
    mixer_out_kernel<false><<<dim3(NBH * 2), dim3(256), 0, stream>>>(
        ei, ew, w2t, w2c, b2, wsb, order2, hws, out);
  }
}

// Round 19
// 152.715 us; speedup vs baseline: 1.1075x; 1.0844x over previous
//
#include <hip/hip_runtime.h>
#include <hip/hip_bf16.h>

// MultiHeadBatchedMixers, group-sorted two-kernel structure (no atomics):
//   prepack+sort: w1t,w2t,x,w1c,w2c,b1,b2 -> bf16 ws in FRAGMENT-PACKED layout
//       [tile][ks][lane][8]: every MFMA fragment load/store in A/B is a single
//       contiguous 1KB (or 512B) transaction instead of 16-64 strided segments.
//   Kernel A (grid 1536x256, XCD-chunked, group-ordered): H = GELU(W1c@X@W1t^T+B1)
//   Kernel B (grid 768x256, XCD-chunked, group-ordered): 4 waves = 2k x 2wq,
//       64c x 64n per wave; LDS combine; plain f32 stores
// bf16 MFMA 16x16x32, f32 accumulate.
// NOTE (R8/R10): VGPR+AGPR share one file; never min-waves-bound MFMA kernels.
// NOTE (R12-R14): cost tracks load instructions & intensity; 64x64 tiles optimal.
// NOTE (R15/R17): acc-lifetime splits and manual double-buffering are no-ops.
// NOTE (R18): A was invariant at 80us across occupancy/intensity/pipelining ->
// bound by MEMORY SEGMENT RATE (strided fragment access = 16-64 segments/instr).
// This round: fragment-packed ws layouts make all hot accesses contiguous.

namespace {
constexpr int NHEAD = 12, NTOK = 256, HDIM = 64, HIDD = 512, NBATCH = 32, TOPK = 2;
constexpr int NCHAIN = NBATCH * NHEAD * TOPK;  // 768
constexpr int NBH = NBATCH * NHEAD;            // 384
constexpr int NGROUP = 8 * NHEAD;              // 96

// Kernel A LDS: per-wave T1^T [64 e][64 d] bf16, pitch +16B
constexpr int P_T1 = HDIM * 2 + 16;   // 144
constexpr int T1_W = 64 * P_T1;       // 9216
constexpr int SMA_TOTAL = 4 * T1_W;   // 36864
// Kernel B LDS: per-wave T3^T [64 n][64 c] (4 waves); combine aliases [0,32768)
constexpr int P_T3 = HDIM * 2 + 16;   // 144
constexpr int T3_W = 64 * P_T3;       // 9216
constexpr int SMB_TOTAL = 4 * T3_W;   // 36864

// ws element layout (bf16 shorts): [H][w1t][w2t][x][b1][b2][w1c][w2c], then orders
constexpr size_t SZ_H    = (size_t)NCHAIN * HDIM * HIDD;          // 25,165,824
constexpr size_t OFF_H   = 0;
constexpr size_t OFF_W1T = OFF_H + SZ_H;
constexpr size_t SZ_W1T  = (size_t)8 * NHEAD * HIDD * NTOK;       // 12,582,912
constexpr size_t OFF_W2T = OFF_W1T + SZ_W1T;
constexpr size_t SZ_W2T  = (size_t)8 * NHEAD * NTOK * HIDD;
constexpr size_t OFF_X   = OFF_W2T + SZ_W2T;
constexpr size_t SZ_X    = (size_t)NBATCH * NHEAD * HDIM * NTOK;  // 6,291,456
constexpr size_t OFF_B1  = OFF_X + SZ_X;
constexpr size_t SZ_B1   = (size_t)8 * NHEAD * HDIM * HIDD;
constexpr size_t OFF_B2  = OFF_B1 + SZ_B1;
constexpr size_t SZ_B2   = (size_t)8 * NHEAD * HDIM * NTOK;
constexpr size_t OFF_W1C = OFF_B2 + SZ_B2;
constexpr size_t SZ_W1C  = (size_t)8 * NHEAD * HDIM * HDIM;       // 393,216
constexpr size_t OFF_W2C = OFF_W1C + SZ_W1C;
constexpr size_t SZ_W2C  = (size_t)8 * NHEAD * HDIM * HDIM;
constexpr size_t TOTEL   = OFF_W2C + SZ_W2C;                      // shorts
constexpr size_t NEED    = TOTEL * 2 + (NCHAIN + NBH) * 4;
}

typedef float f32x4 __attribute__((ext_vector_type(4)));
typedef short bf16x8 __attribute__((ext_vector_type(8)));
typedef short bf16x4 __attribute__((ext_vector_type(4)));

#define MFMA16(a, b, c) __builtin_amdgcn_mfma_f32_16x16x32_bf16((a), (b), (c), 0, 0, 0)

__device__ __forceinline__ short f2bf(float f) {
  union { float f; unsigned u; } v; v.f = f;
  unsigned r = v.u + 0x7fffu + ((v.u >> 16) & 1u);
  return (short)(r >> 16);
}

__device__ __forceinline__ bf16x8 ld_gfrag(const float* p) {
  float4 a = *(const float4*)p;
  float4 b = *(const float4*)(p + 4);
  bf16x8 r;
  r[0] = f2bf(a.x); r[1] = f2bf(a.y); r[2] = f2bf(a.z); r[3] = f2bf(a.w);
  r[4] = f2bf(b.x); r[5] = f2bf(b.y); r[6] = f2bf(b.z); r[7] = f2bf(b.w);
  return r;
}

__device__ __forceinline__ f32x4 bf4f(bf16x4 v) {
  f32x4 r;
  #pragma unroll
  for (int i = 0; i < 4; ++i) {
    union { unsigned u; float f; } t;
    t.u = ((unsigned)(unsigned short)v[i]) << 16;
    r[i] = t.f;
  }
  return r;
}

// gelu(x) = x * rcp(1 + exp2(-2.30220826 * x * (1 + 0.044715 x^2)))  [err ~1e-7 << bf16]
__device__ __forceinline__ float gelu_fast(float x) {
  float arg = -2.30220826f * x * __builtin_fmaf(0.044715f, x * x, 1.0f);
  float e = __builtin_amdgcn_exp2f(arg);
  return x * __builtin_amdgcn_rcpf(1.0f + e);
}

// XCD-chunk swizzle (nwg % 8 == 0): logical sequence contiguous per XCD.
__device__ __forceinline__ int xcd_chunk(int bx, int nwg) {
  return (bx & 7) * (nwg >> 3) + (bx >> 3);
}

// Fragment-packed offset for a [rows][R] row-major tensor (8-el granularity):
// element (r, n) -> (((r>>4)*(R>>5) + (n>>5))*64 + ((n>>3)&3)*16 + (r&15))*8 + (n&7)
__device__ __forceinline__ size_t pack8(int r, int c8, int R) {
  // c8 = chunk index along row (n = c8*8)
  return (size_t)((((r >> 4) * (R >> 5) + (c8 >> 2)) * 64 + (c8 & 3) * 16 + (r & 15))) * 8;
}

// ---------------- Prepack (+ block-0 group sort), fragment-packed ----------------
__global__ __launch_bounds__(256) void prepack_sort_kernel(
    const float* __restrict__ w1t, const float* __restrict__ w2t,
    const float* __restrict__ x, const float* __restrict__ w1c,
    const float* __restrict__ w2c, const float* __restrict__ b1,
    const float* __restrict__ b2, short* __restrict__ wsb,
    const int* __restrict__ eidx, int* __restrict__ order, int* __restrict__ order2) {
  if (blockIdx.x == 0) {
    __shared__ int keys[NCHAIN];
    __shared__ int keys2[NBH];
    __shared__ int cnt[NGROUP + 1];
    __shared__ int cnt2[NGROUP + 1];
    const int t = threadIdx.x;
    for (int i = t; i <= NGROUP; i += 256) { cnt[i] = 0; cnt2[i] = 0; }
    __syncthreads();
    for (int i = t; i < NCHAIN; i += 256) {
      int h = (i >> 1) % NHEAD;
      int key = eidx[i] * NHEAD + h;
      keys[i] = key;
      atomicAdd(&cnt[key + 1], 1);
    }
    for (int i = t; i < NBH; i += 256) {
      int h = i % NHEAD;
      int key = eidx[i * TOPK] * NHEAD + h;
      keys2[i] = key;
      atomicAdd(&cnt2[key + 1], 1);
    }
    __syncthreads();
    if (t == 0) for (int i = 1; i <= NGROUP; ++i) cnt[i] += cnt[i - 1];
    if (t == 1) for (int i = 1; i <= NGROUP; ++i) cnt2[i] += cnt2[i - 1];
    __syncthreads();
    for (int i = t; i < NCHAIN; i += 256) {
      int pos = atomicAdd(&cnt[keys[i]], 1);  // rank within group (order-agnostic downstream)
      order[pos] = i;
    }
    for (int i = t; i < NBH; i += 256) {
      int pos = atomicAdd(&cnt2[keys2[i]], 1);
      order2[pos] = i;
    }
  }

  // Big tensors: 8-el chunks, coalesced reads, packed scattered 16B writes.
  const size_t n1 = SZ_W1T / 8, n2 = n1 + SZ_W2T / 8, n3 = n2 + SZ_X / 8,
               n4 = n3 + SZ_W1C / 8, n5 = n4 + SZ_W2C / 8;
  for (size_t i = (size_t)blockIdx.x * blockDim.x + threadIdx.x; i < n5;
       i += (size_t)gridDim.x * blockDim.x) {
    const float* s; size_t base; int slabSh, rSh, R;  // slab size = 1<<slabSh el, row = R el
    size_t j;
    if (i < n1)      { j = i;      s = w1t; base = OFF_W1T; slabSh = 17; R = 256; }
    else if (i < n2) { j = i - n1; s = w2t; base = OFF_W2T; slabSh = 17; R = 512; }
    else if (i < n3) { j = i - n2; s = x;   base = OFF_X;   slabSh = 14; R = 256; }
    else if (i < n4) { j = i - n3; s = w1c; base = OFF_W1C; slabSh = 12; R = 64;  }
    else             { j = i - n4; s = w2c; base = OFF_W2C; slabSh = 12; R = 64;  }
    const size_t el = j * 8;
    const size_t slab = el >> slabSh;
    const int rem = (int)(el & ((1u << slabSh) - 1));
    const int r = rem / R, c8 = (rem % R) >> 3;
    bf16x8 v = ld_gfrag(s + el);
    *(bf16x8*)(wsb + base + (slab << slabSh) + pack8(r, c8, R)) = v;
  }

  // Bias tensors: 8-el chunks -> two packed bf16x4 writes.
  const size_t m1 = SZ_B1 / 8, m2 = m1 + SZ_B2 / 8;
  for (size_t i = (size_t)blockIdx.x * blockDim.x + threadIdx.x; i < m2;
       i += (size_t)gridDim.x * blockDim.x) {
    const float* s; size_t base; int slabSh, R;
    size_t j;
    if (i < m1) { j = i;      s = b1; base = OFF_B1; slabSh = 15; R = 512; }
    else        { j = i - m1; s = b2; base = OFF_B2; slabSh = 14; R = 256; }
    const size_t el = j * 8;
    const size_t slab = el >> slabSh;
    const int rem = (int)(el & ((1u << slabSh) - 1));
    const int r = rem / R, n0 = rem % R;
    bf16x8 v = ld_gfrag(s + el);
    #pragma unroll
    for (int hxf = 0; hxf < 2; ++hxf) {
      const int e4 = (n0 >> 2) + hxf;
      size_t off = base + (slab << slabSh) +
                   (size_t)((((r >> 4) * (R >> 4) + (e4 >> 2)) * 64 + (e4 & 3) * 16 + (r & 15))) * 4;
      bf16x4 p;
      #pragma unroll
      for (int q = 0; q < 4; ++q) p[q] = v[hxf * 4 + q];
      *(bf16x4*)(wsb + off) = p;
    }
  }
}

// ---------------- Kernel A (64 e per wave; fragment-packed loads/stores) ----------------
// grid = 768*2. L = xcd_chunk(bx,1536): sid = L>>1 -> chain = order[sid], eblk = L&1.
template <bool PP>
__global__ __launch_bounds__(256) void mixer_h_kernel(
    const float* __restrict__ x, const int* __restrict__ eidx,
    const float* __restrict__ w1t, const float* __restrict__ w1c, const float* __restrict__ b1,
    const short* __restrict__ wsb, const int* __restrict__ order, short* __restrict__ hws) {
  __shared__ __align__(16) char smem[SMA_TOTAL];
  const int L = xcd_chunk(blockIdx.x, NCHAIN * 2);
  const int sid = L >> 1, eblk = L & 1;
  const int bhk = PP ? order[sid] : sid;
  const int h = (bhk >> 1) % NHEAD;
  const int tid = threadIdx.x, w = tid >> 6, lane = tid & 63, lr = lane & 15, lg = lane >> 4;

  const int e = eidx[bhk];
  const size_t eh = (size_t)e * NHEAD + h;
  short* H = hws + (size_t)bhk * HDIM * HIDD;

  const int e0 = eblk * 256 + w * 64;
  const int et0 = e0 >> 4;          // global e-tile base (16-wide tiles)
  const int ks0B = e0 >> 5;         // H-fragment ks base (32-wide)

  const short* W1Tp = wsb + OFF_W1T + (eh << 17);
  const short* Xp   = wsb + OFF_X + ((size_t)(bhk >> 1) << 14);
  const short* W1Cp = wsb + OFF_W1C + (eh << 12);
  const short* B1p  = wsb + OFF_B1 + (eh << 15);

  // MFMA1: T1[d][e] = sum_n X[d,n]*W1t[e,n];  A=X (m=d), B=W1t (n=e), k=n
  f32x4 acc1[4][4];  // [et][dt]
  #pragma unroll
  for (int et = 0; et < 4; ++et)
    #pragma unroll
    for (int dt = 0; dt < 4; ++dt) acc1[et][dt] = (f32x4){0.f, 0.f, 0.f, 0.f};
  #pragma unroll
  for (int ks = 0; ks < 8; ++ks) {
    bf16x8 wfr[4];
    #pragma unroll
    for (int et = 0; et < 4; ++et) {
      if (PP) wfr[et] = *(const bf16x8*)(W1Tp + (size_t)(((et0 + et) * 8 + ks) * 512) + lane * 8);
      else    wfr[et] = ld_gfrag(w1t + eh * HIDD * NTOK +
                                 (size_t)(e0 + et * 16 + lr) * NTOK + ks * 32 + lg * 8);
    }
    #pragma unroll
    for (int dt = 0; dt < 4; ++dt) {
      bf16x8 xfr;
      if (PP) xfr = *(const bf16x8*)(Xp + (size_t)((dt * 8 + ks) * 512) + lane * 8);
      else    xfr = ld_gfrag(x + (size_t)(bhk >> 1) * HDIM * NTOK +
                             (size_t)(dt * 16 + lr) * NTOK + ks * 32 + lg * 8);
      #pragma unroll
      for (int et = 0; et < 4; ++et) acc1[et][dt] = MFMA16(xfr, wfr[et], acc1[et][dt]);
    }
  }

  // relayout T1^T via wave-private LDS (col=e=lr, row=d=dt*16+lg*4+i) -> [e][d]
  char* t1 = smem + w * T1_W;
  #pragma unroll
  for (int et = 0; et < 4; ++et)
    #pragma unroll
    for (int dt = 0; dt < 4; ++dt) {
      bf16x4 p;
      #pragma unroll
      for (int i = 0; i < 4; ++i) p[i] = f2bf(acc1[et][dt][i]);
      *(bf16x4*)(t1 + (et * 16 + lr) * P_T1 + (dt * 16 + lg * 4) * 2) = p;
    }

  // MFMA2: T2^T[e][c] = sum_d T1^T[e,d]*W1c[c,d] + B1;  D: col=c=lr, row=e=lg*4+i
  f32x4 acc2[4][4];  // [et][ct]
  #pragma unroll
  for (int et = 0; et < 4; ++et)
    #pragma unroll
    for (int ct = 0; ct < 4; ++ct) {
      if (PP) {
        bf16x4 bb = *(const bf16x4*)(B1p + (size_t)((ct * 32 + et0 + et) * 256) + lane * 4);
        acc2[et][ct] = bf4f(bb);
      } else {
        acc2[et][ct] = *(const f32x4*)(b1 + eh * HDIM * HIDD +
                                       (size_t)(ct * 16 + lr) * HIDD + e0 + et * 16 + lg * 4);
      }
    }
  #pragma unroll
  for (int ks = 0; ks < 2; ++ks) {
    bf16x8 a[4];
    #pragma unroll
    for (int et = 0; et < 4; ++et)
      a[et] = *(const bf16x8*)(t1 + (et * 16 + lr) * P_T1 + (ks * 32 + lg * 8) * 2);
    #pragma unroll
    for (int ct = 0; ct < 4; ++ct) {
      bf16x8 bfr;
      if (PP) bfr = *(const bf16x8*)(W1Cp + (size_t)((ct * 2 + ks) * 512) + lane * 8);
      else    bfr = ld_gfrag(w1c + eh * HDIM * HDIM +
                             (size_t)(ct * 16 + lr) * HDIM + ks * 32 + lg * 8);
      #pragma unroll
      for (int et = 0; et < 4; ++et) acc2[et][ct] = MFMA16(a[et], bfr, acc2[et][ct]);
    }
  }

  // GELU + store H fragment-packed: H'[ct][ksB][lane][8]
  //   element (c=ct*16+lr, e=e0+et*16+lg*4+i): ksB=ks0B+(et>>1), lgB=(et&1)*2+(lg>>1)
  #pragma unroll
  for (int et = 0; et < 4; ++et) {
    const int ksB = ks0B + (et >> 1);
    const int lgB = (et & 1) * 2 + (lg >> 1);
    #pragma unroll
    for (int ct = 0; ct < 4; ++ct) {
      bf16x4 g;
      #pragma unroll
      for (int i = 0; i < 4; ++i) g[i] = f2bf(gelu_fast(acc2[et][ct][i]));
      if (PP) {
        *(bf16x4*)(H + (size_t)((ct * 16 + ksB) * 512) + (lgB * 16 + lr) * 8 + (lg & 1) * 4) = g;
      } else {
        *(bf16x4*)(H + (size_t)(ct * 16 + lr) * HIDD + e0 + et * 16 + lg * 4) = g;
      }
    }
  }
}

// ---------------- Kernel B v6 (64c x 64n per wave; fragment-packed loads) ----------------
// grid = 768 x 256. L = xcd_chunk(bx, 768): sid = L>>1 -> bh = order2[sid], nhalf = L&1.
// Wave w: kk = w>>1, wq = w&1; n rows [nhalf*128 + wq*64, +64). k=1 waves publish
// weighted partials via LDS (aliases dead t3), k=0 waves combine + plain f32 stores.
template <bool PP>
__global__ __launch_bounds__(256) void mixer_out_kernel(
    const int* __restrict__ eidx, const float* __restrict__ ewt,
    const float* __restrict__ w2t, const float* __restrict__ w2c, const float* __restrict__ b2,
    const short* __restrict__ wsb, const int* __restrict__ order2,
    const short* __restrict__ hws, float* __restrict__ out) {
  __shared__ __align__(16) char smem[SMB_TOTAL];
  const int L = xcd_chunk(blockIdx.x, NBH * 2);
  const int sid = L >> 1, nhalf = L & 1;
  const int bh = PP ? order2[sid] : sid;
  const int h = bh % NHEAD;
  const int tid = threadIdx.x, w = tid >> 6, lane = tid & 63, lr = lane & 15, lg = lane >> 4;
  const int kk = w >> 1, wq = w & 1;
  const int nb = nhalf * 128 + wq * 64;
  const int nt0 = nb >> 4;
  char* t3 = smem + w * T3_W;
  float* OUT = out + (size_t)bh * HDIM * NTOK;

  const int e = eidx[bh * TOPK + kk];
  const float wk = ewt[bh * TOPK + kk];
  const size_t eh = (size_t)e * NHEAD + h;
  const short* Hk = hws + (size_t)(bh * TOPK + kk) * HDIM * HIDD;
  const short* W2Tp = wsb + OFF_W2T + (eh << 17);
  const short* W2Cp = wsb + OFF_W2C + (eh << 12);
  const short* B2p  = wsb + OFF_B2 + (eh << 14);

  // MFMA3: T3[c][n] = sum_e H[c,e]*W2t[n,e];  A=H (m=c), B=W2t (n=n), k=e
  f32x4 acc3[4][4];  // [ct][nt]
  #pragma unroll
  for (int ct = 0; ct < 4; ++ct)
    #pragma unroll
    for (int nt = 0; nt < 4; ++nt) acc3[ct][nt] = (f32x4){0.f, 0.f, 0.f, 0.f};
  #pragma unroll 4
  for (int ks = 0; ks < 16; ++ks) {
    bf16x8 a[4];
    #pragma unroll
    for (int ct = 0; ct < 4; ++ct) {
      if (PP) a[ct] = *(const bf16x8*)(Hk + (size_t)((ct * 16 + ks) * 512) + lane * 8);
      else    a[ct] = *(const bf16x8*)(Hk + (size_t)(ct * 16 + lr) * HIDD + ks * 32 + lg * 8);
    }
    #pragma unroll
    for (int nt = 0; nt < 4; ++nt) {
      bf16x8 bfr;
      if (PP) bfr = *(const bf16x8*)(W2Tp + (size_t)(((nt0 + nt) * 16 + ks) * 512) + lane * 8);
      else    bfr = ld_gfrag(w2t + eh * NTOK * HIDD +
                             (size_t)(nb + nt * 16 + lr) * HIDD + ks * 32 + lg * 8);
      #pragma unroll
      for (int ct = 0; ct < 4; ++ct) acc3[ct][nt] = MFMA16(a[ct], bfr, acc3[ct][nt]);
    }
  }

  // relayout T3^T via wave-private LDS (col=n=lr, row=c=ct*16+lg*4+i) -> [n][c]
  #pragma unroll
  for (int ct = 0; ct < 4; ++ct)
    #pragma unroll
    for (int nt = 0; nt < 4; ++nt) {
      bf16x4 p;
      #pragma unroll
      for (int i = 0; i < 4; ++i) p[i] = f2bf(acc3[ct][nt][i]);
      *(bf16x4*)(t3 + (nt * 16 + lr) * P_T3 + (ct * 16 + lg * 4) * 2) = p;
    }

  // MFMA4: OUT^T[n][co] = sum_c T3^T[n,c]*W2c[co,c]
  f32x4 acc4[4][4];  // [nt][cot]
  #pragma unroll
  for (int nt = 0; nt < 4; ++nt)
    #pragma unroll
    for (int ct = 0; ct < 4; ++ct) acc4[nt][ct] = (f32x4){0.f, 0.f, 0.f, 0.f};
  #pragma unroll
  for (int ks = 0; ks < 2; ++ks) {
    bf16x8 a[4];
    #pragma unroll
    for (int nt = 0; nt < 4; ++nt)
      a[nt] = *(const bf16x8*)(t3 + (nt * 16 + lr) * P_T3 + (ks * 32 + lg * 8) * 2);
    #pragma unroll
    for (int ct = 0; ct < 4; ++ct) {
      bf16x8 bfr;
      if (PP) bfr = *(const bf16x8*)(W2Cp + (size_t)((ct * 2 + ks) * 512) + lane * 8);
      else    bfr = ld_gfrag(w2c + eh * HDIM * HDIM +
                             (size_t)(ct * 16 + lr) * HDIM + ks * 32 + lg * 8);
      #pragma unroll
      for (int nt = 0; nt < 4; ++nt) acc4[nt][ct] = MFMA16(a[nt], bfr, acc4[nt][ct]);
    }
  }

  // weighted partial in place: acc4 = wk*(acc4 + B2)  (col=co=lr, row=n=lg*4+i)
  #pragma unroll
  for (int nt = 0; nt < 4; ++nt)
    #pragma unroll
    for (int cot = 0; cot < 4; ++cot) {
      f32x4 bb;
      if (PP) bb = bf4f(*(const bf16x4*)(B2p + (size_t)((cot * 16 + nt0 + nt) * 256) + lane * 4));
      else    bb = *(const f32x4*)(b2 + eh * HDIM * NTOK +
                                   (size_t)(cot * 16 + lr) * NTOK + nb + nt * 16 + lg * 4);
      #pragma unroll
      for (int i = 0; i < 4; ++i) acc4[nt][cot][i] = wk * (acc4[nt][cot][i] + bb[i]);
    }

  __syncthreads();  // all waves done reading their t3 (comb aliases t3 region)

  // k=1 waves publish partials: comb[wq] = [64 n][64 co] f32 at offset wq*16384
  if (kk == 1) {
    float* comb = (float*)(smem + wq * 16384);
    #pragma unroll
    for (int nt = 0; nt < 4; ++nt)
      #pragma unroll
      for (int cot = 0; cot < 4; ++cot) {
        const int co = cot * 16 + lr;
        #pragma unroll
        for (int i = 0; i < 4; ++i)
          comb[(nt * 16 + lg * 4 + i) * 64 + co] = acc4[nt][cot][i];
      }
  }
  __syncthreads();

  // k=0 waves combine + store (each (co,n) written exactly once across the grid)
  if (kk == 0) {
    const float* comb = (const float*)(smem + wq * 16384);
    #pragma unroll
    for (int nt = 0; nt < 4; ++nt)
      #pragma unroll
      for (int cot = 0; cot < 4; ++cot) {
        const int co = cot * 16 + lr;
        const int n0 = nb + nt * 16 + lg * 4;
        f32x4 v;
        #pragma unroll
        for (int i = 0; i < 4; ++i)
          v[i] = acc4[nt][cot][i] + comb[(nt * 16 + lg * 4 + i) * 64 + co];
        *(f32x4*)(OUT + (size_t)co * NTOK + n0) = v;
      }
  }
}

extern "C" void kernel_launch(void* const* d_in, const int* in_sizes, int n_in,
                              void* d_out, int out_size, void* d_ws, size_t ws_size,
                              hipStream_t stream) {
  const float* x   = (const float*)d_in[0];
  const int*   ei  = (const int*)d_in[1];
  const float* ew  = (const float*)d_in[2];
  const float* w1t = (const float*)d_in[3];
  const float* w1c = (const float*)d_in[4];
  const float* b1  = (const float*)d_in[5];
  const float* w2t = (const float*)d_in[6];
  const float* w2c = (const float*)d_in[7];
  const float* b2  = (const float*)d_in[8];
  float* out = (float*)d_out;
  short* wsb = (short*)d_ws;
  short* hws = wsb + OFF_H;
  int* order  = (int*)(wsb + TOTEL);
  int* order2 = order + NCHAIN;

  if (ws_size >= NEED) {
    prepack_sort_kernel<<<dim3(2048), dim3(256), 0, stream>>>(
        w1t, w2t, x, w1c, w2c, b1, b2, wsb, ei, order, order2);
    mixer_h_kernel<true><<<dim3(NCHAIN * 2), dim3(256), 0, stream>>>(
        x, ei, w1t, w1c, b1, wsb, order, hws);
    mixer_out_kernel<true><<<dim3(NBH * 2), dim3(256), 0, stream>>>(
        ei, ew, w2t, w2c, b2, wsb, order2, hws, out);
  } else {
    mixer_h_kernel<false><<<dim3(NCHAIN * 2), dim3(256), 0, stream>>>(
        x, ei, w1t, w1c, b1, wsb, order, hws);
    mixer_out_kernel<false><<<dim3(NBH * 2), dim3(256), 0, stream>>>(
        ei, ew, w2t, w2c, b2, wsb, order2, hws, out);
  }
}

// Round 20
// 133.550 us; speedup vs baseline: 1.2664x; 1.1435x over previous
//
#include <hip/hip_runtime.h>
#include <hip/hip_bf16.h>

// MultiHeadBatchedMixers, group-sorted two-kernel structure (no atomics):
//   prepack+sort (DEST-MAJOR): w1t,w2t,x,w1c,w2c,b1,b2 -> bf16 ws in
//       FRAGMENT-PACKED layout [tile][ks][lane][8]. Dest-linear iteration ->
//       contiguous 1KB wave stores + 16x128B gathered reads (R19 was source-major:
//       scattered 16B writes made prepack itself segment-bound at 80us).
//   Kernel A (grid 1536x256, XCD-chunked, group-ordered): H = GELU(W1c@X@W1t^T+B1)
//   Kernel B (grid 768x256, XCD-chunked, group-ordered): 4 waves = 2k x 2wq,
//       64c x 64n per wave; LDS combine; plain f32 stores
// bf16 MFMA 16x16x32, f32 accumulate.
// NOTE (R8/R10): VGPR+AGPR share one file; never min-waves-bound MFMA kernels.
// NOTE (R12-R14): cost tracks load instructions & intensity; 64x64 tiles optimal.
// NOTE (R15/R17): acc-lifetime splits and manual double-buffering are no-ops.
// NOTE (R18/R19): the binding resource is MEMORY SEGMENTS per instruction;
// fragment-packing A/B cut their time 140->72us. Same fix now applied to prepack.

namespace {
constexpr int NHEAD = 12, NTOK = 256, HDIM = 64, HIDD = 512, NBATCH = 32, TOPK = 2;
constexpr int NCHAIN = NBATCH * NHEAD * TOPK;  // 768
constexpr int NBH = NBATCH * NHEAD;            // 384
constexpr int NGROUP = 8 * NHEAD;              // 96

// Kernel A LDS: per-wave T1^T [64 e][64 d] bf16, pitch +16B
constexpr int P_T1 = HDIM * 2 + 16;   // 144
constexpr int T1_W = 64 * P_T1;       // 9216
constexpr int SMA_TOTAL = 4 * T1_W;   // 36864
// Kernel B LDS: per-wave T3^T [64 n][64 c] (4 waves); combine aliases [0,32768)
constexpr int P_T3 = HDIM * 2 + 16;   // 144
constexpr int T3_W = 64 * P_T3;       // 9216
constexpr int SMB_TOTAL = 4 * T3_W;   // 36864

// ws element layout (bf16 shorts): [H][w1t][w2t][x][b1][b2][w1c][w2c], then orders
constexpr size_t SZ_H    = (size_t)NCHAIN * HDIM * HIDD;          // 25,165,824
constexpr size_t OFF_H   = 0;
constexpr size_t OFF_W1T = OFF_H + SZ_H;
constexpr size_t SZ_W1T  = (size_t)8 * NHEAD * HIDD * NTOK;       // 12,582,912
constexpr size_t OFF_W2T = OFF_W1T + SZ_W1T;
constexpr size_t SZ_W2T  = (size_t)8 * NHEAD * NTOK * HIDD;
constexpr size_t OFF_X   = OFF_W2T + SZ_W2T;
constexpr size_t SZ_X    = (size_t)NBATCH * NHEAD * HDIM * NTOK;  // 6,291,456
constexpr size_t OFF_B1  = OFF_X + SZ_X;
constexpr size_t SZ_B1   = (size_t)8 * NHEAD * HDIM * HIDD;
constexpr size_t OFF_B2  = OFF_B1 + SZ_B1;
constexpr size_t SZ_B2   = (size_t)8 * NHEAD * HDIM * NTOK;
constexpr size_t OFF_W1C = OFF_B2 + SZ_B2;
constexpr size_t SZ_W1C  = (size_t)8 * NHEAD * HDIM * HDIM;       // 393,216
constexpr size_t OFF_W2C = OFF_W1C + SZ_W1C;
constexpr size_t SZ_W2C  = (size_t)8 * NHEAD * HDIM * HDIM;
constexpr size_t TOTEL   = OFF_W2C + SZ_W2C;                      // shorts
constexpr size_t NEED    = TOTEL * 2 + (NCHAIN + NBH) * 4;
}

typedef float f32x4 __attribute__((ext_vector_type(4)));
typedef short bf16x8 __attribute__((ext_vector_type(8)));
typedef short bf16x4 __attribute__((ext_vector_type(4)));

#define MFMA16(a, b, c) __builtin_amdgcn_mfma_f32_16x16x32_bf16((a), (b), (c), 0, 0, 0)

__device__ __forceinline__ short f2bf(float f) {
  union { float f; unsigned u; } v; v.f = f;
  unsigned r = v.u + 0x7fffu + ((v.u >> 16) & 1u);
  return (short)(r >> 16);
}

__device__ __forceinline__ bf16x8 ld_gfrag(const float* p) {
  float4 a = *(const float4*)p;
  float4 b = *(const float4*)(p + 4);
  bf16x8 r;
  r[0] = f2bf(a.x); r[1] = f2bf(a.y); r[2] = f2bf(a.z); r[3] = f2bf(a.w);
  r[4] = f2bf(b.x); r[5] = f2bf(b.y); r[6] = f2bf(b.z); r[7] = f2bf(b.w);
  return r;
}

__device__ __forceinline__ f32x4 bf4f(bf16x4 v) {
  f32x4 r;
  #pragma unroll
  for (int i = 0; i < 4; ++i) {
    union { unsigned u; float f; } t;
    t.u = ((unsigned)(unsigned short)v[i]) << 16;
    r[i] = t.f;
  }
  return r;
}

// gelu(x) = x * rcp(1 + exp2(-2.30220826 * x * (1 + 0.044715 x^2)))  [err ~1e-7 << bf16]
__device__ __forceinline__ float gelu_fast(float x) {
  float arg = -2.30220826f * x * __builtin_fmaf(0.044715f, x * x, 1.0f);
  float e = __builtin_amdgcn_exp2f(arg);
  return x * __builtin_amdgcn_rcpf(1.0f + e);
}

// XCD-chunk swizzle (nwg % 8 == 0): logical sequence contiguous per XCD.
__device__ __forceinline__ int xcd_chunk(int bx, int nwg) {
  return (bx & 7) * (nwg >> 3) + (bx >> 3);
}

// ---------------- Prepack (+ block-0 group sort), DEST-MAJOR fragment pack ----------------
// Forward map (used by A/B readers), per slab of a [rows][R] tensor:
//   dstChunk(r, c8) = ((r>>4)*(R>>5) + (c8>>2))*64 + (c8&3)*16 + (r&15)
// Here we iterate dest-linear and invert: writes contiguous, reads gathered.
__global__ __launch_bounds__(256) void prepack_sort_kernel(
    const float* __restrict__ w1t, const float* __restrict__ w2t,
    const float* __restrict__ x, const float* __restrict__ w1c,
    const float* __restrict__ w2c, const float* __restrict__ b1,
    const float* __restrict__ b2, short* __restrict__ wsb,
    const int* __restrict__ eidx, int* __restrict__ order, int* __restrict__ order2) {
  if (blockIdx.x == 0) {
    __shared__ int keys[NCHAIN];
    __shared__ int keys2[NBH];
    __shared__ int cnt[NGROUP + 1];
    __shared__ int cnt2[NGROUP + 1];
    const int t = threadIdx.x;
    for (int i = t; i <= NGROUP; i += 256) { cnt[i] = 0; cnt2[i] = 0; }
    __syncthreads();
    for (int i = t; i < NCHAIN; i += 256) {
      int h = (i >> 1) % NHEAD;
      int key = eidx[i] * NHEAD + h;
      keys[i] = key;
      atomicAdd(&cnt[key + 1], 1);
    }
    for (int i = t; i < NBH; i += 256) {
      int h = i % NHEAD;
      int key = eidx[i * TOPK] * NHEAD + h;
      keys2[i] = key;
      atomicAdd(&cnt2[key + 1], 1);
    }
    __syncthreads();
    if (t == 0) for (int i = 1; i <= NGROUP; ++i) cnt[i] += cnt[i - 1];
    if (t == 1) for (int i = 1; i <= NGROUP; ++i) cnt2[i] += cnt2[i - 1];
    __syncthreads();
    for (int i = t; i < NCHAIN; i += 256) {
      int pos = atomicAdd(&cnt[keys[i]], 1);  // rank within group (order-agnostic downstream)
      order[pos] = i;
    }
    for (int i = t; i < NBH; i += 256) {
      int pos = atomicAdd(&cnt2[keys2[i]], 1);
      order2[pos] = i;
    }
  }

  // Big tensors (8-el dest chunks): contiguous writes, gathered 32B reads.
  const size_t n1 = SZ_W1T / 8, n2 = n1 + SZ_W2T / 8, n3 = n2 + SZ_X / 8,
               n4 = n3 + SZ_W1C / 8, n5 = n4 + SZ_W2C / 8;
  for (size_t i = (size_t)blockIdx.x * blockDim.x + threadIdx.x; i < n5;
       i += (size_t)gridDim.x * blockDim.x) {
    const float* s; size_t base; int slabSh, R, tprSh;  // tpr = R>>5 tiles per row-band
    size_t j;
    if (i < n1)      { j = i;      s = w1t; base = OFF_W1T; slabSh = 17; R = 256; tprSh = 3; }
    else if (i < n2) { j = i - n1; s = w2t; base = OFF_W2T; slabSh = 17; R = 512; tprSh = 4; }
    else if (i < n3) { j = i - n2; s = x;   base = OFF_X;   slabSh = 14; R = 256; tprSh = 3; }
    else if (i < n4) { j = i - n3; s = w1c; base = OFF_W1C; slabSh = 12; R = 64;  tprSh = 1; }
    else             { j = i - n4; s = w2c; base = OFF_W2C; slabSh = 12; R = 64;  tprSh = 1; }
    const size_t el = j * 8;                        // dest element offset (linear)
    const size_t slab = el >> slabSh;
    const int dstChunk = (int)((el & (((size_t)1 << slabSh) - 1)) >> 3);
    const int frag = dstChunk >> 6, lane = dstChunk & 63;
    const int c8 = ((frag & ((1 << tprSh) - 1)) << 2) + (lane >> 4);
    const int r  = ((frag >> tprSh) << 4) + (lane & 15);
    bf16x8 v = ld_gfrag(s + (slab << slabSh) + (size_t)r * R + c8 * 8);
    *(bf16x8*)(wsb + base + el) = v;
  }

  // Bias tensors (4-el dest chunks): contiguous 8B writes, gathered 16B reads.
  // Forward: dst4(r, e4) = ((r>>4)*(R>>4) + (e4>>2))*64 + (e4&3)*16 + (r&15)
  const size_t m1 = SZ_B1 / 4, m2 = m1 + SZ_B2 / 4;
  for (size_t i = (size_t)blockIdx.x * blockDim.x + threadIdx.x; i < m2;
       i += (size_t)gridDim.x * blockDim.x) {
    const float* s; size_t base; int slabSh, R, tprSh;  // tpr = R>>4
    size_t j;
    if (i < m1) { j = i;      s = b1; base = OFF_B1; slabSh = 15; R = 512; tprSh = 5; }
    else        { j = i - m1; s = b2; base = OFF_B2; slabSh = 14; R = 256; tprSh = 4; }
    const size_t el = j * 4;
    const size_t slab = el >> slabSh;
    const int dst4 = (int)((el & (((size_t)1 << slabSh) - 1)) >> 2);
    const int frag = dst4 >> 6, lane = dst4 & 63;
    const int e4 = ((frag & ((1 << tprSh) - 1)) << 2) + (lane >> 4);
    const int r  = ((frag >> tprSh) << 4) + (lane & 15);
    const float4 sv = *(const float4*)(s + (slab << slabSh) + (size_t)r * R + e4 * 4);
    bf16x4 p;
    p[0] = f2bf(sv.x); p[1] = f2bf(sv.y); p[2] = f2bf(sv.z); p[3] = f2bf(sv.w);
    *(bf16x4*)(wsb + base + el) = p;
  }
}

// ---------------- Kernel A (64 e per wave; fragment-packed loads/stores) ----------------
// grid = 768*2. L = xcd_chunk(bx,1536): sid = L>>1 -> chain = order[sid], eblk = L&1.
template <bool PP>
__global__ __launch_bounds__(256) void mixer_h_kernel(
    const float* __restrict__ x, const int* __restrict__ eidx,
    const float* __restrict__ w1t, const float* __restrict__ w1c, const float* __restrict__ b1,
    const short* __restrict__ wsb, const int* __restrict__ order, short* __restrict__ hws) {
  __shared__ __align__(16) char smem[SMA_TOTAL];
  const int L = xcd_chunk(blockIdx.x, NCHAIN * 2);
  const int sid = L >> 1, eblk = L & 1;
  const int bhk = PP ? order[sid] : sid;
  const int h = (bhk >> 1) % NHEAD;
  const int tid = threadIdx.x, w = tid >> 6, lane = tid & 63, lr = lane & 15, lg = lane >> 4;

  const int e = eidx[bhk];
  const size_t eh = (size_t)e * NHEAD + h;
  short* H = hws + (size_t)bhk * HDIM * HIDD;

  const int e0 = eblk * 256 + w * 64;
  const int et0 = e0 >> 4;          // global e-tile base (16-wide tiles)
  const int ks0B = e0 >> 5;         // H-fragment ks base (32-wide)

  const short* W1Tp = wsb + OFF_W1T + (eh << 17);
  const short* Xp   = wsb + OFF_X + ((size_t)(bhk >> 1) << 14);
  const short* W1Cp = wsb + OFF_W1C + (eh << 12);
  const short* B1p  = wsb + OFF_B1 + (eh << 15);

  // MFMA1: T1[d][e] = sum_n X[d,n]*W1t[e,n];  A=X (m=d), B=W1t (n=e), k=n
  f32x4 acc1[4][4];  // [et][dt]
  #pragma unroll
  for (int et = 0; et < 4; ++et)
    #pragma unroll
    for (int dt = 0; dt < 4; ++dt) acc1[et][dt] = (f32x4){0.f, 0.f, 0.f, 0.f};
  #pragma unroll
  for (int ks = 0; ks < 8; ++ks) {
    bf16x8 wfr[4];
    #pragma unroll
    for (int et = 0; et < 4; ++et) {
      if (PP) wfr[et] = *(const bf16x8*)(W1Tp + (size_t)(((et0 + et) * 8 + ks) * 512) + lane * 8);
      else    wfr[et] = ld_gfrag(w1t + eh * HIDD * NTOK +
                                 (size_t)(e0 + et * 16 + lr) * NTOK + ks * 32 + lg * 8);
    }
    #pragma unroll
    for (int dt = 0; dt < 4; ++dt) {
      bf16x8 xfr;
      if (PP) xfr = *(const bf16x8*)(Xp + (size_t)((dt * 8 + ks) * 512) + lane * 8);
      else    xfr = ld_gfrag(x + (size_t)(bhk >> 1) * HDIM * NTOK +
                             (size_t)(dt * 16 + lr) * NTOK + ks * 32 + lg * 8);
      #pragma unroll
      for (int et = 0; et < 4; ++et) acc1[et][dt] = MFMA16(xfr, wfr[et], acc1[et][dt]);
    }
  }

  // relayout T1^T via wave-private LDS (col=e=lr, row=d=dt*16+lg*4+i) -> [e][d]
  char* t1 = smem + w * T1_W;
  #pragma unroll
  for (int et = 0; et < 4; ++et)
    #pragma unroll
    for (int dt = 0; dt < 4; ++dt) {
      bf16x4 p;
      #pragma unroll
      for (int i = 0; i < 4; ++i) p[i] = f2bf(acc1[et][dt][i]);
      *(bf16x4*)(t1 + (et * 16 + lr) * P_T1 + (dt * 16 + lg * 4) * 2) = p;
    }

  // MFMA2: T2^T[e][c] = sum_d T1^T[e,d]*W1c[c,d] + B1;  D: col=c=lr, row=e=lg*4+i
  f32x4 acc2[4][4];  // [et][ct]
  #pragma unroll
  for (int et = 0; et < 4; ++et)
    #pragma unroll
    for (int ct = 0; ct < 4; ++ct) {
      if (PP) {
        bf16x4 bb = *(const bf16x4*)(B1p + (size_t)((ct * 32 + et0 + et) * 256) + lane * 4);
        acc2[et][ct] = bf4f(bb);
      } else {
        acc2[et][ct] = *(const f32x4*)(b1 + eh * HDIM * HIDD +
                                       (size_t)(ct * 16 + lr) * HIDD + e0 + et * 16 + lg * 4);
      }
    }
  #pragma unroll
  for (int ks = 0; ks < 2; ++ks) {
    bf16x8 a[4];
    #pragma unroll
    for (int et = 0; et < 4; ++et)
      a[et] = *(const bf16x8*)(t1 + (et * 16 + lr) * P_T1 + (ks * 32 + lg * 8) * 2);
    #pragma unroll
    for (int ct = 0; ct < 4; ++ct) {
      bf16x8 bfr;
      if (PP) bfr = *(const bf16x8*)(W1Cp + (size_t)((ct * 2 + ks) * 512) + lane * 8);
      else    bfr = ld_gfrag(w1c + eh * HDIM * HDIM +
                             (size_t)(ct * 16 + lr) * HDIM + ks * 32 + lg * 8);
      #pragma unroll
      for (int et = 0; et < 4; ++et) acc2[et][ct] = MFMA16(a[et], bfr, acc2[et][ct]);
    }
  }

  // GELU + store H fragment-packed: H'[ct][ksB][lane][8]
  //   element (c=ct*16+lr, e=e0+et*16+lg*4+i): ksB=ks0B+(et>>1), lgB=(et&1)*2+(lg>>1)
  #pragma unroll
  for (int et = 0; et < 4; ++et) {
    const int ksB = ks0B + (et >> 1);
    const int lgB = (et & 1) * 2 + (lg >> 1);
    #pragma unroll
    for (int ct = 0; ct < 4; ++ct) {
      bf16x4 g;
      #pragma unroll
      for (int i = 0; i < 4; ++i) g[i] = f2bf(gelu_fast(acc2[et][ct][i]));
      if (PP) {
        *(bf16x4*)(H + (size_t)((ct * 16 + ksB) * 512) + (lgB * 16 + lr) * 8 + (lg & 1) * 4) = g;
      } else {
        *(bf16x4*)(H + (size_t)(ct * 16 + lr) * HIDD + e0 + et * 16 + lg * 4) = g;
      }
    }
  }
}

// ---------------- Kernel B v6 (64c x 64n per wave; fragment-packed loads) ----------------
// grid = 768 x 256. L = xcd_chunk(bx, 768): sid = L>>1 -> bh = order2[sid], nhalf = L&1.
// Wave w: kk = w>>1, wq = w&1; n rows [nhalf*128 + wq*64, +64). k=1 waves publish
// weighted partials via LDS (aliases dead t3), k=0 waves combine + plain f32 stores.
template <bool PP>
__global__ __launch_bounds__(256) void mixer_out_kernel(
    const int* __restrict__ eidx, const float* __restrict__ ewt,
    const float* __restrict__ w2t, const float* __restrict__ w2c, const float* __restrict__ b2,
    const short* __restrict__ wsb, const int* __restrict__ order2,
    const short* __restrict__ hws, float* __restrict__ out) {
  __shared__ __align__(16) char smem[SMB_TOTAL];
  const int L = xcd_chunk(blockIdx.x, NBH * 2);
  const int sid = L >> 1, nhalf = L & 1;
  const int bh = PP ? order2[sid] : sid;
  const int h = bh % NHEAD;
  const int tid = threadIdx.x, w = tid >> 6, lane = tid & 63, lr = lane & 15, lg = lane >> 4;
  const int kk = w >> 1, wq = w & 1;
  const int nb = nhalf * 128 + wq * 64;
  const int nt0 = nb >> 4;
  char* t3 = smem + w * T3_W;
  float* OUT = out + (size_t)bh * HDIM * NTOK;

  const int e = eidx[bh * TOPK + kk];
  const float wk = ewt[bh * TOPK + kk];
  const size_t eh = (size_t)e * NHEAD + h;
  const short* Hk = hws + (size_t)(bh * TOPK + kk) * HDIM * HIDD;
  const short* W2Tp = wsb + OFF_W2T + (eh << 17);
  const short* W2Cp = wsb + OFF_W2C + (eh << 12);
  const short* B2p  = wsb + OFF_B2 + (eh << 14);

  // MFMA3: T3[c][n] = sum_e H[c,e]*W2t[n,e];  A=H (m=c), B=W2t (n=n), k=e
  f32x4 acc3[4][4];  // [ct][nt]
  #pragma unroll
  for (int ct = 0; ct < 4; ++ct)
    #pragma unroll
    for (int nt = 0; nt < 4; ++nt) acc3[ct][nt] = (f32x4){0.f, 0.f, 0.f, 0.f};
  #pragma unroll 4
  for (int ks = 0; ks < 16; ++ks) {
    bf16x8 a[4];
    #pragma unroll
    for (int ct = 0; ct < 4; ++ct) {
      if (PP) a[ct] = *(const bf16x8*)(Hk + (size_t)((ct * 16 + ks) * 512) + lane * 8);
      else    a[ct] = *(const bf16x8*)(Hk + (size_t)(ct * 16 + lr) * HIDD + ks * 32 + lg * 8);
    }
    #pragma unroll
    for (int nt = 0; nt < 4; ++nt) {
      bf16x8 bfr;
      if (PP) bfr = *(const bf16x8*)(W2Tp + (size_t)(((nt0 + nt) * 16 + ks) * 512) + lane * 8);
      else    bfr = ld_gfrag(w2t + eh * NTOK * HIDD +
                             (size_t)(nb + nt * 16 + lr) * HIDD + ks * 32 + lg * 8);
      #pragma unroll
      for (int ct = 0; ct < 4; ++ct) acc3[ct][nt] = MFMA16(a[ct], bfr, acc3[ct][nt]);
    }
  }

  // relayout T3^T via wave-private LDS (col=n=lr, row=c=ct*16+lg*4+i) -> [n][c]
  #pragma unroll
  for (int ct = 0; ct < 4; ++ct)
    #pragma unroll
    for (int nt = 0; nt < 4; ++nt) {
      bf16x4 p;
      #pragma unroll
      for (int i = 0; i < 4; ++i) p[i] = f2bf(acc3[ct][nt][i]);
      *(bf16x4*)(t3 + (nt * 16 + lr) * P_T3 + (ct * 16 + lg * 4) * 2) = p;
    }

  // MFMA4: OUT^T[n][co] = sum_c T3^T[n,c]*W2c[co,c]
  f32x4 acc4[4][4];  // [nt][cot]
  #pragma unroll
  for (int nt = 0; nt < 4; ++nt)
    #pragma unroll
    for (int ct = 0; ct < 4; ++ct) acc4[nt][ct] = (f32x4){0.f, 0.f, 0.f, 0.f};
  #pragma unroll
  for (int ks = 0; ks < 2; ++ks) {
    bf16x8 a[4];
    #pragma unroll
    for (int nt = 0; nt < 4; ++nt)
      a[nt] = *(const bf16x8*)(t3 + (nt * 16 + lr) * P_T3 + (ks * 32 + lg * 8) * 2);
    #pragma unroll
    for (int ct = 0; ct < 4; ++ct) {
      bf16x8 bfr;
      if (PP) bfr = *(const bf16x8*)(W2Cp + (size_t)((ct * 2 + ks) * 512) + lane * 8);
      else    bfr = ld_gfrag(w2c + eh * HDIM * HDIM +
                             (size_t)(ct * 16 + lr) * HDIM + ks * 32 + lg * 8);
      #pragma unroll
      for (int nt = 0; nt < 4; ++nt) acc4[nt][ct] = MFMA16(a[nt], bfr, acc4[nt][ct]);
    }
  }

  // weighted partial in place: acc4 = wk*(acc4 + B2)  (col=co=lr, row=n=lg*4+i)
  #pragma unroll
  for (int nt = 0; nt < 4; ++nt)
    #pragma unroll
    for (int cot = 0; cot < 4; ++cot) {
      f32x4 bb;
      if (PP) bb = bf4f(*(const bf16x4*)(B2p + (size_t)((cot * 16 + nt0 + nt) * 256) + lane * 4));
      else    bb = *(const f32x4*)(b2 + eh * HDIM * NTOK +
                                   (size_t)(cot * 16 + lr) * NTOK + nb + nt * 16 + lg * 4);
      #pragma unroll
      for (int i = 0; i < 4; ++i) acc4[nt][cot][i] = wk * (acc4[nt][cot][i] + bb[i]);
    }

  __syncthreads();  // all waves done reading their t3 (comb aliases t3 region)

  // k=1 waves publish partials: comb[wq] = [64 n][64 co] f32 at offset wq*16384
  if (kk == 1) {
    float* comb = (float*)(smem + wq * 16384);
    #pragma unroll
    for (int nt = 0; nt < 4; ++nt)
      #pragma unroll
      for (int cot = 0; cot < 4; ++cot) {
        const int co = cot * 16 + lr;
        #pragma unroll
        for (int i = 0; i < 4; ++i)
          comb[(nt * 16 + lg * 4 + i) * 64 + co] = acc4[nt][cot][i];
      }
  }
  __syncthreads();

  // k=0 waves combine + store (each (co,n) written exactly once across the grid)
  if (kk == 0) {
    const float* comb = (const float*)(smem + wq * 16384);
    #pragma unroll
    for (int nt = 0; nt < 4; ++nt)
      #pragma unroll
      for (int cot = 0; cot < 4; ++cot) {
        const int co = cot * 16 + lr;
        const int n0 = nb + nt * 16 + lg * 4;
        f32x4 v;
        #pragma unroll
        for (int i = 0; i < 4; ++i)
          v[i] = acc4[nt][cot][i] + comb[(nt * 16 + lg * 4 + i) * 64 + co];
        *(f32x4*)(OUT + (size_t)co * NTOK + n0) = v;
      }
  }
}

extern "C" void kernel_launch(void* const* d_in, const int* in_sizes, int n_in,
                              void* d_out, int out_size, void* d_ws, size_t ws_size,
                              hipStream_t stream) {
  const float* x   = (const float*)d_in[0];
  const int*   ei  = (const int*)d_in[1];
  const float* ew  = (const float*)d_in[2];
  const float* w1t = (const float*)d_in[3];
  const float* w1c = (const float*)d_in[4];
  const float* b1  = (const float*)d_in[5];
  const float* w2t = (const float*)d_in[6];
  const float* w2c = (const float*)d_in[7];
  const float* b2  = (const float*)d_in[8];
  float* out = (float*)d_out;
  short* wsb = (short*)d_ws;
  short* hws = wsb + OFF_H;
  int* order  = (int*)(wsb + TOTEL);
  int* order2 = order + NCHAIN;

  if (ws_size >= NEED) {
    prepack_sort_kernel<<<dim3(2048), dim3(256), 0, stream>>>(
        w1t, w2t, x, w1c, w2c, b1, b2, wsb, ei, order, order2);
    mixer_h_kernel<true><<<dim3(NCHAIN * 2), dim3(256), 0, stream>>>(
        x, ei, w1t, w1c, b1, wsb, order, hws);
    mixer_out_kernel<true><<<dim3(NBH * 2), dim3(256), 0, stream>>>(
        ei, ew, w2t, w2c, b2, wsb, order2, hws, out);
  } else {
    mixer_h_kernel<false><<<dim3(NCHAIN * 2), dim3(256), 0, stream>>>(
        x, ei, w1t, w1c, b1, wsb, order, hws);
    mixer_out_kernel<false><<<dim3(NBH * 2), dim3(256), 0, stream>>>(
        ei, ew, w2t, w2c, b2, wsb, order2, hws, out);
  }
}

// Round 21
// 132.554 us; speedup vs baseline: 1.2759x; 1.0075x over previous
//
#include <hip/hip_runtime.h>
#include <hip/hip_bf16.h>

// MultiHeadBatchedMixers, group-sorted two-kernel structure (no atomics):
//   prepack+sort (LDS-STAGED TRANSPOSE): per 16-row band, stream source linearly
//       -> convert+permute into swizzled LDS tile -> stream dest linearly.
//       Both global sides fully coalesced (R19: scattered writes; R20: gathered reads).
//   Kernel A (grid 1536x256, XCD-chunked, group-ordered): H = GELU(W1c@X@W1t^T+B1)
//   Kernel B (grid 768x256, XCD-chunked, group-ordered): 4 waves = 2k x 2wq,
//       64c x 64n per wave; LDS combine; plain f32 stores
// bf16 MFMA 16x16x32, f32 accumulate. Fragment-packed ws layout [tile][ks][lane][8].
// NOTE (R8/R10): VGPR+AGPR share one file; never min-waves-bound MFMA kernels.
// NOTE (R12-R14): cost tracks load instructions & intensity; 64x64 tiles optimal.
// NOTE (R15/R17): acc-lifetime splits and manual double-buffering are no-ops.
// NOTE (R18-R20): the binding resource is MEMORY SEGMENTS per instruction.

namespace {
constexpr int NHEAD = 12, NTOK = 256, HDIM = 64, HIDD = 512, NBATCH = 32, TOPK = 2;
constexpr int NCHAIN = NBATCH * NHEAD * TOPK;  // 768
constexpr int NBH = NBATCH * NHEAD;            // 384
constexpr int NGROUP = 8 * NHEAD;              // 96

// Kernel A LDS: per-wave T1^T [64 e][64 d] bf16, pitch +16B
constexpr int P_T1 = HDIM * 2 + 16;   // 144
constexpr int T1_W = 64 * P_T1;       // 9216
constexpr int SMA_TOTAL = 4 * T1_W;   // 36864
// Kernel B LDS: per-wave T3^T [64 n][64 c] (4 waves); combine aliases [0,32768)
constexpr int P_T3 = HDIM * 2 + 16;   // 144
constexpr int T3_W = 64 * P_T3;       // 9216
constexpr int SMB_TOTAL = 4 * T3_W;   // 36864

// ws element layout (bf16 shorts): [H][w1t][w2t][x][b1][b2][w1c][w2c], then orders
constexpr size_t SZ_H    = (size_t)NCHAIN * HDIM * HIDD;          // 25,165,824
constexpr size_t OFF_H   = 0;
constexpr size_t OFF_W1T = OFF_H + SZ_H;
constexpr size_t SZ_W1T  = (size_t)8 * NHEAD * HIDD * NTOK;       // 12,582,912
constexpr size_t OFF_W2T = OFF_W1T + SZ_W1T;
constexpr size_t SZ_W2T  = (size_t)8 * NHEAD * NTOK * HIDD;
constexpr size_t OFF_X   = OFF_W2T + SZ_W2T;
constexpr size_t SZ_X    = (size_t)NBATCH * NHEAD * HDIM * NTOK;  // 6,291,456
constexpr size_t OFF_B1  = OFF_X + SZ_X;
constexpr size_t SZ_B1   = (size_t)8 * NHEAD * HDIM * HIDD;
constexpr size_t OFF_B2  = OFF_B1 + SZ_B1;
constexpr size_t SZ_B2   = (size_t)8 * NHEAD * HDIM * NTOK;
constexpr size_t OFF_W1C = OFF_B2 + SZ_B2;
constexpr size_t SZ_W1C  = (size_t)8 * NHEAD * HDIM * HDIM;       // 393,216
constexpr size_t OFF_W2C = OFF_W1C + SZ_W1C;
constexpr size_t SZ_W2C  = (size_t)8 * NHEAD * HDIM * HDIM;
constexpr size_t TOTEL   = OFF_W2C + SZ_W2C;                      // shorts
constexpr size_t NEED    = TOTEL * 2 + (NCHAIN + NBH) * 4;

// prepack band counts (band = 16 rows x R cols, contiguous on both sides)
constexpr int NB_W1T = (int)(SZ_W1T / (16 * 256));  // 3072
constexpr int NB_W2T = (int)(SZ_W2T / (16 * 512));  // 1536
constexpr int NB_X   = (int)(SZ_X   / (16 * 256));  // 1536
constexpr int NB_W1C = (int)(SZ_W1C / (16 * 64));   // 384
constexpr int NB_W2C = (int)(SZ_W2C / (16 * 64));   // 384
constexpr int NB_B1  = (int)(SZ_B1  / (16 * 512));  // 384
constexpr int NB_B2  = (int)(SZ_B2  / (16 * 256));  // 384
constexpr int NB_TOT = NB_W1T + NB_W2T + NB_X + NB_W1C + NB_W2C + NB_B1 + NB_B2;  // 7680
}

typedef float f32x4 __attribute__((ext_vector_type(4)));
typedef short bf16x8 __attribute__((ext_vector_type(8)));
typedef short bf16x4 __attribute__((ext_vector_type(4)));

#define MFMA16(a, b, c) __builtin_amdgcn_mfma_f32_16x16x32_bf16((a), (b), (c), 0, 0, 0)

__device__ __forceinline__ short f2bf(float f) {
  union { float f; unsigned u; } v; v.f = f;
  unsigned r = v.u + 0x7fffu + ((v.u >> 16) & 1u);
  return (short)(r >> 16);
}

__device__ __forceinline__ bf16x8 ld_gfrag(const float* p) {
  float4 a = *(const float4*)p;
  float4 b = *(const float4*)(p + 4);
  bf16x8 r;
  r[0] = f2bf(a.x); r[1] = f2bf(a.y); r[2] = f2bf(a.z); r[3] = f2bf(a.w);
  r[4] = f2bf(b.x); r[5] = f2bf(b.y); r[6] = f2bf(b.z); r[7] = f2bf(b.w);
  return r;
}

__device__ __forceinline__ f32x4 bf4f(bf16x4 v) {
  f32x4 r;
  #pragma unroll
  for (int i = 0; i < 4; ++i) {
    union { unsigned u; float f; } t;
    t.u = ((unsigned)(unsigned short)v[i]) << 16;
    r[i] = t.f;
  }
  return r;
}

// gelu(x) = x * rcp(1 + exp2(-2.30220826 * x * (1 + 0.044715 x^2)))  [err ~1e-7 << bf16]
__device__ __forceinline__ float gelu_fast(float x) {
  float arg = -2.30220826f * x * __builtin_fmaf(0.044715f, x * x, 1.0f);
  float e = __builtin_amdgcn_exp2f(arg);
  return x * __builtin_amdgcn_rcpf(1.0f + e);
}

// XCD-chunk swizzle (nwg % 8 == 0): logical sequence contiguous per XCD.
__device__ __forceinline__ int xcd_chunk(int bx, int nwg) {
  return (bx & 7) * (nwg >> 3) + (bx >> 3);
}

// LDS swizzles (bank-spread, self-inverse XOR within 128-chunk groups)
__device__ __forceinline__ int swz16(int c) { return c ^ ((c >> 4) & 7); }         // 16B chunks
__device__ __forceinline__ int swz8(int c)  { return c ^ (((c >> 4) & 3) << 1); }  // 8B chunks

// ---------------- Prepack (+ block-0 group sort), LDS-staged transpose ----------------
// Per band (16 rows x R): within-band permutation
//   g8:  chunk8(r,c8) = (c8>>2)*64 + (c8&3)*16 + r   (= forward fragment layout)
//   g4:  chunk4(r,e4) = (e4>>2)*64 + (e4&3)*16 + r
// Source and dest element offsets of band bb are both bb*16*R (verified contiguous).
__global__ __launch_bounds__(256) void prepack_sort_kernel(
    const float* __restrict__ w1t, const float* __restrict__ w2t,
    const float* __restrict__ x, const float* __restrict__ w1c,
    const float* __restrict__ w2c, const float* __restrict__ b1,
    const float* __restrict__ b2, short* __restrict__ wsb,
    const int* __restrict__ eidx, int* __restrict__ order, int* __restrict__ order2) {
  if (blockIdx.x == 0) {
    __shared__ int keys[NCHAIN];
    __shared__ int keys2[NBH];
    __shared__ int cnt[NGROUP + 1];
    __shared__ int cnt2[NGROUP + 1];
    const int t = threadIdx.x;
    for (int i = t; i <= NGROUP; i += 256) { cnt[i] = 0; cnt2[i] = 0; }
    __syncthreads();
    for (int i = t; i < NCHAIN; i += 256) {
      int h = (i >> 1) % NHEAD;
      int key = eidx[i] * NHEAD + h;
      keys[i] = key;
      atomicAdd(&cnt[key + 1], 1);
    }
    for (int i = t; i < NBH; i += 256) {
      int h = i % NHEAD;
      int key = eidx[i * TOPK] * NHEAD + h;
      keys2[i] = key;
      atomicAdd(&cnt2[key + 1], 1);
    }
    __syncthreads();
    if (t == 0) for (int i = 1; i <= NGROUP; ++i) cnt[i] += cnt[i - 1];
    if (t == 1) for (int i = 1; i <= NGROUP; ++i) cnt2[i] += cnt2[i - 1];
    __syncthreads();
    for (int i = t; i < NCHAIN; i += 256) {
      int pos = atomicAdd(&cnt[keys[i]], 1);  // rank within group (order-agnostic downstream)
      order[pos] = i;
    }
    for (int i = t; i < NBH; i += 256) {
      int pos = atomicAdd(&cnt2[keys2[i]], 1);
      order2[pos] = i;
    }
    __syncthreads();
  }

  __shared__ __align__(16) short tile[8192];  // 16KB: one band (max 16x512 bf16)

  for (int band = blockIdx.x; band < NB_TOT; band += gridDim.x) {
    const float* s; size_t dbase; int R; bool g8;
    int bb = band;
    if (bb < NB_W1T)                 { s = w1t; dbase = OFF_W1T; R = 256; g8 = true; }
    else if ((bb -= NB_W1T) < NB_W2T){ s = w2t; dbase = OFF_W2T; R = 512; g8 = true; }
    else if ((bb -= NB_W2T) < NB_X)  { s = x;   dbase = OFF_X;   R = 256; g8 = true; }
    else if ((bb -= NB_X) < NB_W1C)  { s = w1c; dbase = OFF_W1C; R = 64;  g8 = true; }
    else if ((bb -= NB_W1C) < NB_W2C){ s = w2c; dbase = OFF_W2C; R = 64;  g8 = true; }
    else if ((bb -= NB_W2C) < NB_B1) { s = b1;  dbase = OFF_B1;  R = 512; g8 = false; }
    else                             { bb -= NB_B1; s = b2; dbase = OFF_B2; R = 256; g8 = false; }

    const size_t eloff = (size_t)bb * 16 * R;
    const int n8 = (16 * R) / 8;  // 8-el groups in band

    // stage 1: linear read + convert + permuted (swizzled) LDS store
    if (g8) {
      for (int l8 = threadIdx.x; l8 < n8; l8 += 256) {
        const int l = l8 * 8;
        const int r = l / R, c8 = (l % R) >> 3;
        const int chunk = (c8 >> 2) * 64 + (c8 & 3) * 16 + r;
        *(bf16x8*)(tile + swz16(chunk) * 8) = ld_gfrag(s + eloff + l);
      }
    } else {
      for (int l8 = threadIdx.x; l8 < n8; l8 += 256) {
        const int l = l8 * 8;
        const int r = l / R, c = l % R;
        bf16x8 v = ld_gfrag(s + eloff + l);
        #pragma unroll
        for (int q = 0; q < 2; ++q) {
          const int e4 = (c >> 2) + q;
          const int chunk = (e4 >> 2) * 64 + (e4 & 3) * 16 + r;
          bf16x4 p;
          #pragma unroll
          for (int i = 0; i < 4; ++i) p[i] = v[q * 4 + i];
          *(bf16x4*)(tile + swz8(chunk) * 4) = p;
        }
      }
    }
    __syncthreads();

    // stage 2: swizzled LDS read + linear global write
    if (g8) {
      for (int l8 = threadIdx.x; l8 < n8; l8 += 256)
        *(bf16x8*)(wsb + dbase + eloff + (size_t)l8 * 8) =
            *(const bf16x8*)(tile + swz16(l8) * 8);
    } else {
      for (int l8 = threadIdx.x; l8 < n8; l8 += 256) {
        const int l4 = l8 * 2;
        bf16x8 v;
        bf16x4 a = *(const bf16x4*)(tile + swz8(l4) * 4);
        bf16x4 b = *(const bf16x4*)(tile + swz8(l4 + 1) * 4);
        #pragma unroll
        for (int i = 0; i < 4; ++i) { v[i] = a[i]; v[4 + i] = b[i]; }
        *(bf16x8*)(wsb + dbase + eloff + (size_t)l8 * 8) = v;
      }
    }
    __syncthreads();  // protect tile before next band
  }
}

// ---------------- Kernel A (64 e per wave; fragment-packed loads/stores) ----------------
// grid = 768*2. L = xcd_chunk(bx,1536): sid = L>>1 -> chain = order[sid], eblk = L&1.
template <bool PP>
__global__ __launch_bounds__(256) void mixer_h_kernel(
    const float* __restrict__ x, const int* __restrict__ eidx,
    const float* __restrict__ w1t, const float* __restrict__ w1c, const float* __restrict__ b1,
    const short* __restrict__ wsb, const int* __restrict__ order, short* __restrict__ hws) {
  __shared__ __align__(16) char smem[SMA_TOTAL];
  const int L = xcd_chunk(blockIdx.x, NCHAIN * 2);
  const int sid = L >> 1, eblk = L & 1;
  const int bhk = PP ? order[sid] : sid;
  const int h = (bhk >> 1) % NHEAD;
  const int tid = threadIdx.x, w = tid >> 6, lane = tid & 63, lr = lane & 15, lg = lane >> 4;

  const int e = eidx[bhk];
  const size_t eh = (size_t)e * NHEAD + h;
  short* H = hws + (size_t)bhk * HDIM * HIDD;

  const int e0 = eblk * 256 + w * 64;
  const int et0 = e0 >> 4;          // global e-tile base (16-wide tiles)
  const int ks0B = e0 >> 5;         // H-fragment ks base (32-wide)

  const short* W1Tp = wsb + OFF_W1T + (eh << 17);
  const short* Xp   = wsb + OFF_X + ((size_t)(bhk >> 1) << 14);
  const short* W1Cp = wsb + OFF_W1C + (eh << 12);
  const short* B1p  = wsb + OFF_B1 + (eh << 15);

  // MFMA1: T1[d][e] = sum_n X[d,n]*W1t[e,n];  A=X (m=d), B=W1t (n=e), k=n
  f32x4 acc1[4][4];  // [et][dt]
  #pragma unroll
  for (int et = 0; et < 4; ++et)
    #pragma unroll
    for (int dt = 0; dt < 4; ++dt) acc1[et][dt] = (f32x4){0.f, 0.f, 0.f, 0.f};
  #pragma unroll
  for (int ks = 0; ks < 8; ++ks) {
    bf16x8 wfr[4];
    #pragma unroll
    for (int et = 0; et < 4; ++et) {
      if (PP) wfr[et] = *(const bf16x8*)(W1Tp + (size_t)(((et0 + et) * 8 + ks) * 512) + lane * 8);
      else    wfr[et] = ld_gfrag(w1t + eh * HIDD * NTOK +
                                 (size_t)(e0 + et * 16 + lr) * NTOK + ks * 32 + lg * 8);
    }
    #pragma unroll
    for (int dt = 0; dt < 4; ++dt) {
      bf16x8 xfr;
      if (PP) xfr = *(const bf16x8*)(Xp + (size_t)((dt * 8 + ks) * 512) + lane * 8);
      else    xfr = ld_gfrag(x + (size_t)(bhk >> 1) * HDIM * NTOK +
                             (size_t)(dt * 16 + lr) * NTOK + ks * 32 + lg * 8);
      #pragma unroll
      for (int et = 0; et < 4; ++et) acc1[et][dt] = MFMA16(xfr, wfr[et], acc1[et][dt]);
    }
  }

  // relayout T1^T via wave-private LDS (col=e=lr, row=d=dt*16+lg*4+i) -> [e][d]
  char* t1 = smem + w * T1_W;
  #pragma unroll
  for (int et = 0; et < 4; ++et)
    #pragma unroll
    for (int dt = 0; dt < 4; ++dt) {
      bf16x4 p;
      #pragma unroll
      for (int i = 0; i < 4; ++i) p[i] = f2bf(acc1[et][dt][i]);
      *(bf16x4*)(t1 + (et * 16 + lr) * P_T1 + (dt * 16 + lg * 4) * 2) = p;
    }

  // MFMA2: T2^T[e][c] = sum_d T1^T[e,d]*W1c[c,d] + B1;  D: col=c=lr, row=e=lg*4+i
  f32x4 acc2[4][4];  // [et][ct]
  #pragma unroll
  for (int et = 0; et < 4; ++et)
    #pragma unroll
    for (int ct = 0; ct < 4; ++ct) {
      if (PP) {
        bf16x4 bb = *(const bf16x4*)(B1p + (size_t)((ct * 32 + et0 + et) * 256) + lane * 4);
        acc2[et][ct] = bf4f(bb);
      } else {
        acc2[et][ct] = *(const f32x4*)(b1 + eh * HDIM * HIDD +
                                       (size_t)(ct * 16 + lr) * HIDD + e0 + et * 16 + lg * 4);
      }
    }
  #pragma unroll
  for (int ks = 0; ks < 2; ++ks) {
    bf16x8 a[4];
    #pragma unroll
    for (int et = 0; et < 4; ++et)
      a[et] = *(const bf16x8*)(t1 + (et * 16 + lr) * P_T1 + (ks * 32 + lg * 8) * 2);
    #pragma unroll
    for (int ct = 0; ct < 4; ++ct) {
      bf16x8 bfr;
      if (PP) bfr = *(const bf16x8*)(W1Cp + (size_t)((ct * 2 + ks) * 512) + lane * 8);
      else    bfr = ld_gfrag(w1c + eh * HDIM * HDIM +
                             (size_t)(ct * 16 + lr) * HDIM + ks * 32 + lg * 8);
      #pragma unroll
      for (int et = 0; et < 4; ++et) acc2[et][ct] = MFMA16(a[et], bfr, acc2[et][ct]);
    }
  }

  // GELU + store H fragment-packed: H'[ct][ksB][lane][8]
  //   element (c=ct*16+lr, e=e0+et*16+lg*4+i): ksB=ks0B+(et>>1), lgB=(et&1)*2+(lg>>1)
  #pragma unroll
  for (int et = 0; et < 4; ++et) {
    const int ksB = ks0B + (et >> 1);
    const int lgB = (et & 1) * 2 + (lg >> 1);
    #pragma unroll
    for (int ct = 0; ct < 4; ++ct) {
      bf16x4 g;
      #pragma unroll
      for (int i = 0; i < 4; ++i) g[i] = f2bf(gelu_fast(acc2[et][ct][i]));
      if (PP) {
        *(bf16x4*)(H + (size_t)((ct * 16 + ksB) * 512) + (lgB * 16 + lr) * 8 + (lg & 1) * 4) = g;
      } else {
        *(bf16x4*)(H + (size_t)(ct * 16 + lr) * HIDD + e0 + et * 16 + lg * 4) = g;
      }
    }
  }
}

// ---------------- Kernel B v6 (64c x 64n per wave; fragment-packed loads) ----------------
// grid = 768 x 256. L = xcd_chunk(bx, 768): sid = L>>1 -> bh = order2[sid], nhalf = L&1.
// Wave w: kk = w>>1, wq = w&1; n rows [nhalf*128 + wq*64, +64). k=1 waves publish
// weighted partials via LDS (aliases dead t3), k=0 waves combine + plain f32 stores.
template <bool PP>
__global__ __launch_bounds__(256) void mixer_out_kernel(
    const int* __restrict__ eidx, const float* __restrict__ ewt,
    const float* __restrict__ w2t, const float* __restrict__ w2c, const float* __restrict__ b2,
    const short* __restrict__ wsb, const int* __restrict__ order2,
    const short* __restrict__ hws, float* __restrict__ out) {
  __shared__ __align__(16) char smem[SMB_TOTAL];
  const int L = xcd_chunk(blockIdx.x, NBH * 2);
  const int sid = L >> 1, nhalf = L & 1;
  const int bh = PP ? order2[sid] : sid;
  const int h = bh % NHEAD;
  const int tid = threadIdx.x, w = tid >> 6, lane = tid & 63, lr = lane & 15, lg = lane >> 4;
  const int kk = w >> 1, wq = w & 1;
  const int nb = nhalf * 128 + wq * 64;
  const int nt0 = nb >> 4;
  char* t3 = smem + w * T3_W;
  float* OUT = out + (size_t)bh * HDIM * NTOK;

  const int e = eidx[bh * TOPK + kk];
  const float wk = ewt[bh * TOPK + kk];
  const size_t eh = (size_t)e * NHEAD + h;
  const short* Hk = hws + (size_t)(bh * TOPK + kk) * HDIM * HIDD;
  const short* W2Tp = wsb + OFF_W2T + (eh << 17);
  const short* W2Cp = wsb + OFF_W2C + (eh << 12);
  const short* B2p  = wsb + OFF_B2 + (eh << 14);

  // MFMA3: T3[c][n] = sum_e H[c,e]*W2t[n,e];  A=H (m=c), B=W2t (n=n), k=e
  f32x4 acc3[4][4];  // [ct][nt]
  #pragma unroll
  for (int ct = 0; ct < 4; ++ct)
    #pragma unroll
    for (int nt = 0; nt < 4; ++nt) acc3[ct][nt] = (f32x4){0.f, 0.f, 0.f, 0.f};
  #pragma unroll 4
  for (int ks = 0; ks < 16; ++ks) {
    bf16x8 a[4];
    #pragma unroll
    for (int ct = 0; ct < 4; ++ct) {
      if (PP) a[ct] = *(const bf16x8*)(Hk + (size_t)((ct * 16 + ks) * 512) + lane * 8);
      else    a[ct] = *(const bf16x8*)(Hk + (size_t)(ct * 16 + lr) * HIDD + ks * 32 + lg * 8);
    }
    #pragma unroll
    for (int nt = 0; nt < 4; ++nt) {
      bf16x8 bfr;
      if (PP) bfr = *(const bf16x8*)(W2Tp + (size_t)(((nt0 + nt) * 16 + ks) * 512) + lane * 8);
      else    bfr = ld_gfrag(w2t + eh * NTOK * HIDD +
                             (size_t)(nb + nt * 16 + lr) * HIDD + ks * 32 + lg * 8);
      #pragma unroll
      for (int ct = 0; ct < 4; ++ct) acc3[ct][nt] = MFMA16(a[ct], bfr, acc3[ct][nt]);
    }
  }

  // relayout T3^T via wave-private LDS (col=n=lr, row=c=ct*16+lg*4+i) -> [n][c]
  #pragma unroll
  for (int ct = 0; ct < 4; ++ct)
    #pragma unroll
    for (int nt = 0; nt < 4; ++nt) {
      bf16x4 p;
      #pragma unroll
      for (int i = 0; i < 4; ++i) p[i] = f2bf(acc3[ct][nt][i]);
      *(bf16x4*)(t3 + (nt * 16 + lr) * P_T3 + (ct * 16 + lg * 4) * 2) = p;
    }

  // MFMA4: OUT^T[n][co] = sum_c T3^T[n,c]*W2c[co,c]
  f32x4 acc4[4][4];  // [nt][cot]
  #pragma unroll
  for (int nt = 0; nt < 4; ++nt)
    #pragma unroll
    for (int ct = 0; ct < 4; ++ct) acc4[nt][ct] = (f32x4){0.f, 0.f, 0.f, 0.f};
  #pragma unroll
  for (int ks = 0; ks < 2; ++ks) {
    bf16x8 a[4];
    #pragma unroll
    for (int nt = 0; nt < 4; ++nt)
      a[nt] = *(const bf16x8*)(t3 + (nt * 16 + lr) * P_T3 + (ks * 32 + lg * 8) * 2);
    #pragma unroll
    for (int ct = 0; ct < 4; ++ct) {
      bf16x8 bfr;
      if (PP) bfr = *(const bf16x8*)(W2Cp + (size_t)((ct * 2 + ks) * 512) + lane * 8);
      else    bfr = ld_gfrag(w2c + eh * HDIM * HDIM +
                             (size_t)(ct * 16 + lr) * HDIM + ks * 32 + lg * 8);
      #pragma unroll
      for (int nt = 0; nt < 4; ++nt) acc4[nt][ct] = MFMA16(a[nt], bfr, acc4[nt][ct]);
    }
  }

  // weighted partial in place: acc4 = wk*(acc4 + B2)  (col=co=lr, row=n=lg*4+i)
  #pragma unroll
  for (int nt = 0; nt < 4; ++nt)
    #pragma unroll
    for (int cot = 0; cot < 4; ++cot) {
      f32x4 bb;
      if (PP) bb = bf4f(*(const bf16x4*)(B2p + (size_t)((cot * 16 + nt0 + nt) * 256) + lane * 4));
      else    bb = *(const f32x4*)(b2 + eh * HDIM * NTOK +
                                   (size_t)(cot * 16 + lr) * NTOK + nb + nt * 16 + lg * 4);
      #pragma unroll
      for (int i = 0; i < 4; ++i) acc4[nt][cot][i] = wk * (acc4[nt][cot][i] + bb[i]);
    }

  __syncthreads();  // all waves done reading their t3 (comb aliases t3 region)

  // k=1 waves publish partials: comb[wq] = [64 n][64 co] f32 at offset wq*16384
  if (kk == 1) {
    float* comb = (float*)(smem + wq * 16384);
    #pragma unroll
    for (int nt = 0; nt < 4; ++nt)
      #pragma unroll
      for (int cot = 0; cot < 4; ++cot) {
        const int co = cot * 16 + lr;
        #pragma unroll
        for (int i = 0; i < 4; ++i)
          comb[(nt * 16 + lg * 4 + i) * 64 + co] = acc4[nt][cot][i];
      }
  }
  __syncthreads();

  // k=0 waves combine + store (each (co,n) written exactly once across the grid)
  if (kk == 0) {
    const float* comb = (const float*)(smem + wq * 16384);
    #pragma unroll
    for (int nt = 0; nt < 4; ++nt)
      #pragma unroll
      for (int cot = 0; cot < 4; ++cot) {
        const int co = cot * 16 + lr;
        const int n0 = nb + nt * 16 + lg * 4;
        f32x4 v;
        #pragma unroll
        for (int i = 0; i < 4; ++i)
          v[i] = acc4[nt][cot][i] + comb[(nt * 16 + lg * 4 + i) * 64 + co];
        *(f32x4*)(OUT + (size_t)co * NTOK + n0) = v;
      }
  }
}

extern "C" void kernel_launch(void* const* d_in, const int* in_sizes, int n_in,
                              void* d_out, int out_size, void* d_ws, size_t ws_size,
                              hipStream_t stream) {
  const float* x   = (const float*)d_in[0];
  const int*   ei  = (const int*)d_in[1];
  const float* ew  = (const float*)d_in[2];
  const float* w1t = (const float*)d_in[3];
  const float* w1c = (const float*)d_in[4];
  const float* b1  = (const float*)d_in[5];
  const float* w2t = (const float*)d_in[6];
  const float* w2c = (const float*)d_in[7];
  const float* b2  = (const float*)d_in[8];
  float* out = (float*)d_out;
  short* wsb = (short*)d_ws;
  short* hws = wsb + OFF_H;
  int* order  = (int*)(wsb + TOTEL);
  int* order2 = order + NCHAIN;

  if (ws_size >= NEED) {
    prepack_sort_kernel<<<dim3(2048), dim3(256), 0, stream>>>(
        w1t, w2t, x, w1c, w2c, b1, b2, wsb, ei, order, order2);
    mixer_h_kernel<true><<<dim3(NCHAIN * 2), dim3(256), 0, stream>>>(
        x, ei, w1t, w1c, b1, wsb, order, hws);
    mixer_out_kernel<true><<<dim3(NBH * 2), dim3(256), 0, stream>>>(
        ei, ew, w2t, w2c, b2, wsb, order2, hws, out);
  } else {
    mixer_h_kernel<false><<<dim3(NCHAIN * 2), dim3(256), 0, stream>>>(
        x, ei, w1t, w1c, b1, wsb, order, hws);
    mixer_out_kernel<false><<<dim3(NBH * 2), dim3(256), 0, stream>>>(
        ei, ew, w2t, w2c, b2, wsb, order2, hws, out);
  }
}